// Round 13
// baseline (10566.066 us; speedup 1.0000x reference)
//
#include <hip/hip_runtime.h>

typedef unsigned short u16;
typedef unsigned int u32;
typedef __bf16 bf16x8 __attribute__((ext_vector_type(8)));
typedef u16 u16x8 __attribute__((ext_vector_type(8)));
typedef float f32x4 __attribute__((ext_vector_type(4)));
typedef u32 u32x4 __attribute__((ext_vector_type(4)));

#define B_ 16
#define T_ 510
#define H_ 512
#define N_ 4096
#define KSPLIT 2560  // [hi(1280) | lo(1280)]

// workspace offsets (bytes)
#define OFF_ABIG  0ull
#define OFF_BBIG  41943040ull
#define OFF_BIAS  62914560ull
#define OFF_XG    62930944ull
#define OFF_HS    197148672ull
#define OFF_EMIS  230572032ull
#define OFF_V     230735232ull
#define OFF_FLAGS 230735296ull   // flagsA (64 ints)
#define OFF_HBUF  230735552ull   // hbufA (128KB)
// borrowed from the emissions region (written by k_emis only AFTER k_recur):
#define OFF_HBUFB  (OFF_EMIS)              // 128KB
#define OFF_FLAGSB (OFF_EMIS + 131072ull)  // 256B
#define OFF_PROBE  (OFF_EMIS + 131328ull)  // 256B
#define OFF_CTRL   (OFF_EMIS + 131584ull)  // 64B
#define OFF_PROBE2 (OFF_EMIS + 131648ull)  // 256B

#define MAGIC_  0x5EC0FFEE
#define MAGIC2_ 0x7A57C0DE
#define MAGIC3_ 0x3C0DE777
#define POLL_BUDGET 65536
#define PHB_BUDGET  8192
#define ARB_BUDGET  262144

#define GL_LDS(g, s) __builtin_amdgcn_global_load_lds(                      \
    (const __attribute__((address_space(1))) void*)(g),                     \
    (__attribute__((address_space(3))) void*)(s), 16, 0, 0)

__device__ __forceinline__ u16 f2bf(float x) {
  u32 u = __float_as_uint(x);
  u32 r = (u + 0x7fffu + ((u >> 16) & 1u)) >> 16;
  return (u16)r;
}
__device__ __forceinline__ float bf2f(u16 h) { return __uint_as_float(((u32)h) << 16); }

__device__ __forceinline__ int ld_cc(const int* p) {
  int f;
  asm volatile("global_load_dword %0, %1, off sc0 sc1\n\ts_waitcnt vmcnt(0)" : "=v"(f) : "v"(p) : "memory");
  return f;
}
__device__ __forceinline__ int ld_se(const int* p) {
  int f;
  asm volatile("global_load_dword %0, %1, off sc0\n\ts_waitcnt vmcnt(0)" : "=v"(f) : "v"(p) : "memory");
  return f;
}
__device__ __forceinline__ void st_cc(int* p, int v) {
  asm volatile("global_store_dword %0, %1, off sc0 sc1\n\ts_waitcnt vmcnt(0)" :: "v"(p), "v"(v) : "memory");
}
__device__ __forceinline__ void st_plain(int* p, int v) {
  asm volatile("global_store_dword %0, %1, off\n\ts_waitcnt vmcnt(0)" :: "v"(p), "v"(v) : "memory");
}

__device__ __forceinline__ float sigm_f(float x) {  // exact-pass verified (R7/R10/R12)
  float e = __expf(-x);
  return __builtin_amdgcn_rcpf(1.f + e);
}
__device__ __forceinline__ float tanh_f(float x) {
  float e = __expf(2.f * x);
  return 1.f - 2.f * __builtin_amdgcn_rcpf(e + 1.f);
}

// ---------------- K0: lengths + zero all protocol state ----------------
__global__ __launch_bounds__(256) void k_prep(const int* __restrict__ mask, int* __restrict__ V,
                                              int* __restrict__ flagsA, int* __restrict__ flagsB,
                                              int* __restrict__ probe, int* __restrict__ probe2,
                                              int* __restrict__ ctrl) {
  __shared__ int red[4];
  int b = blockIdx.x, tid = threadIdx.x;
  int s = mask[b * 512 + tid] + mask[b * 512 + 256 + tid];
  for (int off = 32; off; off >>= 1) s += __shfl_down(s, off);
  if ((tid & 63) == 0) red[tid >> 6] = s;
  __syncthreads();
  if (tid == 0) V[b] = red[0] + red[1] + red[2] + red[3] - 2;
  if (b == 0 && tid < 64) flagsA[tid] = 0;
  if (b == 2 && tid < 64) flagsB[tid] = 0;
  if (b == 3 && tid < 64) probe[tid] = 0;
  if (b == 4 && tid < 64) probe2[tid] = 0;
  if (b == 1 && tid < 16) ctrl[tid] = 0;
}

// ---------------- valid output ----------------
__global__ __launch_bounds__(256) void k_valid(const int* __restrict__ V, int* __restrict__ out) {
  int idx = blockIdx.x * 256 + threadIdx.x;
  if (idx < B_ * T_) {
    int b = idx / T_, t = idx - b * T_;
    out[B_ * T_ + idx] = (t < V[b]) ? 1 : 0;
  }
}

// ---------------- split x into [hi|lo] bf16, masked ----------------
__global__ __launch_bounds__(320) void k_splitA(const float* __restrict__ emb, const int* __restrict__ V,
                                                u16* __restrict__ Abig) {
  int row = blockIdx.x;
  int k0 = threadIdx.x * 4;
  u16* dst = Abig + (size_t)row * KSPLIT;
  float4 v = {0.f, 0.f, 0.f, 0.f};
  if (row < B_ * T_) {
    int b = row / T_, t = row - b * T_;
    if (t < V[b]) v = *(const float4*)(emb + (size_t)(b * 512 + t + 1) * 1280 + k0);
  }
  float vs[4] = {v.x, v.y, v.z, v.w};
  ushort4 hi, lo;
  u16 h0_ = f2bf(vs[0]); u16 l0_ = f2bf(vs[0] - bf2f(h0_));
  u16 h1_ = f2bf(vs[1]); u16 l1_ = f2bf(vs[1] - bf2f(h1_));
  u16 h2_ = f2bf(vs[2]); u16 l2_ = f2bf(vs[2] - bf2f(h2_));
  u16 h3_ = f2bf(vs[3]); u16 l3_ = f2bf(vs[3] - bf2f(h3_));
  hi.x = h0_; hi.y = h1_; hi.z = h2_; hi.w = h3_;
  lo.x = l0_; lo.y = l1_; lo.z = l2_; lo.w = l3_;
  *(ushort4*)(dst + k0) = hi;
  *(ushort4*)(dst + 1280 + k0) = lo;
}

// ---------------- split W_ih into [hi|lo] bf16 (B^T layout) + bias ----------------
__global__ __launch_bounds__(320) void k_splitB(const float* __restrict__ wf, const float* __restrict__ wb,
                                                const float* __restrict__ bihf, const float* __restrict__ bhhf,
                                                const float* __restrict__ bihb, const float* __restrict__ bhhb,
                                                u16* __restrict__ Bbig, float* __restrict__ bias) {
  int n = blockIdx.x;  // 0..4095
  int k0 = threadIdx.x * 4;
  int d = n >> 11, g = n & 2047;
  const float* w = (d ? wb : wf) + (size_t)g * 1280;
  float4 v = *(const float4*)(w + k0);
  float vs[4] = {v.x, v.y, v.z, v.w};
  ushort4 hi, lo;
  u16 h0_ = f2bf(vs[0]); u16 l0_ = f2bf(vs[0] - bf2f(h0_));
  u16 h1_ = f2bf(vs[1]); u16 l1_ = f2bf(vs[1] - bf2f(h1_));
  u16 h2_ = f2bf(vs[2]); u16 l2_ = f2bf(vs[2] - bf2f(h2_));
  u16 h3_ = f2bf(vs[3]); u16 l3_ = f2bf(vs[3] - bf2f(h3_));
  hi.x = h0_; hi.y = h1_; hi.z = h2_; hi.w = h3_;
  lo.x = l0_; lo.y = l1_; lo.z = l2_; lo.w = l3_;
  u16* dst = Bbig + (size_t)n * KSPLIT;
  *(ushort4*)(dst + k0) = hi;
  *(ushort4*)(dst + 1280 + k0) = lo;
  if (threadIdx.x == 0) bias[n] = d ? (bihb[g] + bhhb[g]) : (bihf[g] + bhhf[g]);
}

// ---------------- Phase A GEMM: C[8192x4096] = Abig * Bbig^T (bf16x3, logical K=3840) ----------------
__global__ __launch_bounds__(256, 2) void k_gemm(const u16* __restrict__ A, const u16* __restrict__ Bt,
                                                 const float* __restrict__ bias, float* __restrict__ C) {
  __shared__ __align__(16) u16 As[128 * 64];
  __shared__ __align__(16) u16 Bs[128 * 64];
  const int tid = threadIdx.x;
  const int w = tid >> 6, l = tid & 63;
  const int wm = w >> 1, wn = w & 1;
  const int bm = blockIdx.x, bn = blockIdx.y;
  f32x4 acc[4][4];
#pragma unroll
  for (int m = 0; m < 4; ++m)
#pragma unroll
    for (int n = 0; n < 4; ++n) acc[m][n] = (f32x4){0.f, 0.f, 0.f, 0.f};

  const int rQ = tid >> 3;
  const int cB = (tid & 7) * 16;
  const char* gA = (const char*)(A + (size_t)(bm * 128) * KSPLIT) + cB;
  const char* gB = (const char*)(Bt + (size_t)(bn * 128) * KSPLIT) + cB;

  for (int kt = 0; kt < 60; ++kt) {
    const int s = kt / 20, ks = kt - s * 20;
    const int aOff = ((s == 2) ? 1280 : 0) + ks * 64;
    const int bOff = ((s == 1) ? 1280 : 0) + ks * 64;
    __syncthreads();
#pragma unroll
    for (int q = 0; q < 4; ++q) {
      GL_LDS(gA + ((size_t)(q * 32 + rQ) * KSPLIT + aOff) * 2, (char*)As + q * 4096 + tid * 16);
      GL_LDS(gB + ((size_t)(q * 32 + rQ) * KSPLIT + bOff) * 2, (char*)Bs + q * 4096 + tid * 16);
    }
    __syncthreads();
#pragma unroll
    for (int kc = 0; kc < 2; ++kc) {
      bf16x8 af[4], bfr[4];
      const int kByte = kc * 64 + (l >> 4) * 16;
#pragma unroll
      for (int m = 0; m < 4; ++m)
        af[m] = *(const bf16x8*)((const char*)As + (wm * 64 + m * 16 + (l & 15)) * 128 + kByte);
#pragma unroll
      for (int n = 0; n < 4; ++n)
        bfr[n] = *(const bf16x8*)((const char*)Bs + (wn * 64 + n * 16 + (l & 15)) * 128 + kByte);
#pragma unroll
      for (int m = 0; m < 4; ++m)
#pragma unroll
        for (int n = 0; n < 4; ++n)
          acc[m][n] = __builtin_amdgcn_mfma_f32_16x16x32_bf16(af[m], bfr[n], acc[m][n], 0, 0, 0);
    }
  }
#pragma unroll
  for (int n = 0; n < 4; ++n) {
    const int gc = bn * 128 + wn * 64 + n * 16 + (l & 15);
    const float bv = bias[gc];
#pragma unroll
    for (int m = 0; m < 4; ++m) {
      const int gr0 = bm * 128 + wm * 64 + m * 16 + (l >> 4) * 4;
#pragma unroll
      for (int r = 0; r < 4; ++r) C[(size_t)(gr0 + r) * N_ + gc] = acc[m][n][r] + bv;
    }
  }
}

// ---------------- recurrence body: 16 blocks x 512 threads per dir ----------------
// Block owns 32 units (sub*32..+31); wave w (0..7) owns units sub*32+w*4..+3 x 4 gates.
// Gate-math thread = (sb=tid>>5, su=tid&31) -> emit/hs/xg all naturally coalesced (no hsh).
// COH=2 FAST: plain stores + sc0 loads (sc0sc1 escape each 256 polls). COH=1 MID: sc0sc1
// loads. COH=0: cross-XCD fallback. R10 lesson: nothing outstanding across the flag
// release - xg prefetch strictly AFTER the flag store. R11 lesson: launch bounds must
// leave >=200 VGPRs (weight cache alone = 128) - (512,1) caps at 256, no spill.
template <int COH>
__device__ void run_recur(int dir, int sub, const float* __restrict__ xg, const float* __restrict__ whh,
                          const float* __restrict__ h0, const float* __restrict__ c0,
                          float* __restrict__ hs, u16* __restrict__ hbuf, int* __restrict__ flags,
                          u16* lds_a, float* epil) {
  const int tid = threadIdx.x;
  const int w = tid >> 6, l = tid & 63;
  const int c = l & 15, kg = l >> 4;
  const int gate = c >> 2, uloc = c & 3;
  const int ug = sub * 32 + w * 4 + uloc;
  constexpr int GB = (COH != 0) ? 9 : 0;

  __syncthreads();  // safe re-entry

  // preload W_hh fragments, split bf16 hi/lo (held in VGPRs)
  bf16x8 whi[16], wlo[16];
  {
    const float* wrow = whh + (size_t)(gate * 512 + ug) * 512 + kg * 8;
#pragma unroll
    for (int kc = 0; kc < 16; ++kc) {
      float4 v0 = *(const float4*)(wrow + kc * 32);
      float4 v1 = *(const float4*)(wrow + kc * 32 + 4);
      float vs[8] = {v0.x, v0.y, v0.z, v0.w, v1.x, v1.y, v1.z, v1.w};
      u16x8 hi, lo;
#pragma unroll
      for (int j = 0; j < 8; ++j) {
        u16 h = f2bf(vs[j]);
        hi[j] = h;
        lo[j] = f2bf(vs[j] - bf2f(h));
      }
      whi[kc] = __builtin_bit_cast(bf16x8, hi);
      wlo[kc] = __builtin_bit_cast(bf16x8, lo);
    }
  }

  const int sb = tid >> 5, su = tid & 31;  // gate-math ownership
  const int gu = sub * 32 + su;
  float creg = c0[(dir * 16 + sb) * 512 + gu];
  {  // publish initial h (split) into parity-0 buffer (one-time); coalesced by construction
    float h = h0[(dir * 16 + sb) * 512 + gu];
    u16 hh = f2bf(h), hl = f2bf(h - bf2f(hh));
    size_t base = (size_t)(dir * 2) * 8192;
    u16* p0 = hbuf + base + sb * 512 + gu;
    if constexpr (COH != 0) {
      asm volatile("global_store_short %0, %1, off\n\tglobal_store_short %2, %3, off\n\ts_waitcnt vmcnt(0)"
                   :: "v"(p0), "v"((u32)hh), "v"(p0 + 8192), "v"((u32)hl) : "memory");
    } else {
      asm volatile("global_store_short %0, %1, off sc0 sc1\n\tglobal_store_short %2, %3, off sc0 sc1\n\ts_waitcnt vmcnt(0)"
                   :: "v"(p0), "v"((u32)hh), "v"(p0 + 8192), "v"((u32)hl) : "memory");
    }
  }
  __syncthreads();
  if (tid == 0) {
    if constexpr (COH != 0) st_plain(flags + dir * 32 + sub, 1 + GB);
    else st_cc(flags + dir * 32 + sub, 1 + GB);
  }

  // xg prefetch for step 0 (issued after release; drains in first poll, overlapped)
  float xv[4];
  {
    const int tr0 = dir ? (T_ - 1) : 0;
#pragma unroll
    for (int g = 0; g < 4; ++g) {
      const float* p = xg + (size_t)(sb * T_ + tr0) * N_ + dir * 2048 + g * 512 + gu;
      asm volatile("global_load_dword %0, %1, off" : "=v"(xv[g]) : "v"(p) : "memory");
    }
  }

  for (int t = 0; t < T_; ++t) {
    const int trow = dir ? (T_ - 1 - t) : t;
    // per-dir barrier: one vectorized 16-flag poll (each flag read by 4 lanes)
    if (w == 0) {
      const int* fp = flags + (dir << 5) + (l & 15);
      int it = 0;
      while (true) {
        int f;
        if constexpr (COH == 2) {
          ++it;
          if ((it & 255) == 0)
            asm volatile("global_load_dword %0, %1, off sc0 sc1\n\ts_waitcnt vmcnt(0)" : "=v"(f) : "v"(fp) : "memory");
          else
            asm volatile("global_load_dword %0, %1, off sc0\n\ts_waitcnt vmcnt(0)" : "=v"(f) : "v"(fp) : "memory");
        } else {
          asm volatile("global_load_dword %0, %1, off sc0 sc1\n\ts_waitcnt vmcnt(0)" : "=v"(f) : "v"(fp) : "memory");
        }
        if (__all(f >= t + 1 + GB)) break;
        if constexpr (COH == 0) __builtin_amdgcn_s_sleep(1);
      }
    }
    __syncthreads();

    // stage h(t) 32KB into LDS: 4 passes x 512 thr x 16B (FAST: L2-served sc0)
    {
      const u16* src = hbuf + (size_t)(((t & 1) * 2 + dir) * 2) * 8192;
      u32x4 v[4];
#pragma unroll
      for (int q = 0; q < 4; ++q) {
        const char* p = (const char*)src + q * 8192 + tid * 16;
        if constexpr (COH == 2)
          asm volatile("global_load_dwordx4 %0, %1, off sc0" : "=v"(v[q]) : "v"(p) : "memory");
        else
          asm volatile("global_load_dwordx4 %0, %1, off sc0 sc1" : "=v"(v[q]) : "v"(p) : "memory");
      }
      asm volatile("s_waitcnt vmcnt(0)" ::: "memory");
      __builtin_amdgcn_sched_barrier(0);
#pragma unroll
      for (int q = 0; q < 4; ++q) {
        int off = q * 8192 + tid * 16;
        int var = off >> 14;
        int rem = off & 16383;
        int b = rem >> 10;
        int inrow = rem & 1023;
        *(u32x4*)((char*)lds_a + var * 16384 + b * 1024 + (inrow ^ ((b & 7) << 4))) = v[q];
      }
    }
    __syncthreads();

    // 6 independent accumulator chains (xg added at epilogue from prefetched regs)
    f32x4 acc0 = (f32x4){0.f, 0.f, 0.f, 0.f};
    f32x4 acc1 = acc0, acc2 = acc0, acc3 = acc0, acc4 = acc0, acc5 = acc0;
#pragma unroll
    for (int kc = 0; kc < 16; ++kc) {
      const int rowb = l & 15;
      const int koff = (kc * 64 + kg * 16) ^ ((rowb & 7) << 4);
      bf16x8 ahi = *(const bf16x8*)((const char*)lds_a + rowb * 1024 + koff);
      bf16x8 alo = *(const bf16x8*)((const char*)lds_a + 16384 + rowb * 1024 + koff);
      if (kc & 1) {
        acc3 = __builtin_amdgcn_mfma_f32_16x16x32_bf16(ahi, whi[kc], acc3, 0, 0, 0);
        acc4 = __builtin_amdgcn_mfma_f32_16x16x32_bf16(ahi, wlo[kc], acc4, 0, 0, 0);
        acc5 = __builtin_amdgcn_mfma_f32_16x16x32_bf16(alo, whi[kc], acc5, 0, 0, 0);
      } else {
        acc0 = __builtin_amdgcn_mfma_f32_16x16x32_bf16(ahi, whi[kc], acc0, 0, 0, 0);
        acc1 = __builtin_amdgcn_mfma_f32_16x16x32_bf16(ahi, wlo[kc], acc1, 0, 0, 0);
        acc2 = __builtin_amdgcn_mfma_f32_16x16x32_bf16(alo, whi[kc], acc2, 0, 0, 0);
      }
    }
    f32x4 acc = ((acc0 + acc3) + (acc1 + acc4)) + (acc2 + acc5);

    // epilogue: cross-wave transpose via LDS (wave stride 324, row stride 20 -> 2-way max)
#pragma unroll
    for (int r = 0; r < 4; ++r) epil[w * 324 + (kg * 4 + r) * 20 + c] = acc[r];
    __syncthreads();
    const int ew = su >> 2, ec = su & 3;
    const float gi = epil[ew * 324 + sb * 20 + 0 + ec] + xv[0];
    const float gf = epil[ew * 324 + sb * 20 + 4 + ec] + xv[1];
    const float gg = epil[ew * 324 + sb * 20 + 8 + ec] + xv[2];
    const float go = epil[ew * 324 + sb * 20 + 12 + ec] + xv[3];
    const float si = sigm_f(gi);
    const float sf = sigm_f(gf);
    const float so = sigm_f(go);
    const float tg = tanh_f(gg);
    creg = sf * creg + si * tg;
    const float h = so * tanh_f(creg);
    // emit: thread owns (sb,su) -> 64B-contiguous per 32-lane group, no redistribution
    {
      u16 hh = f2bf(h), hl = f2bf(h - bf2f(hh));
      size_t base = (size_t)((((t + 1) & 1) * 2 + dir) * 2) * 8192;
      u16* p0 = hbuf + base + sb * 512 + gu;
      if constexpr (COH != 0) {
        asm volatile("global_store_short %0, %1, off\n\tglobal_store_short %2, %3, off\n\ts_waitcnt vmcnt(0)"
                     :: "v"(p0), "v"((u32)hh), "v"(p0 + 8192), "v"((u32)hl) : "memory");
      } else {
        asm volatile("global_store_short %0, %1, off sc0 sc1\n\tglobal_store_short %2, %3, off sc0 sc1\n\ts_waitcnt vmcnt(0)"
                     :: "v"(p0), "v"((u32)hh), "v"(p0 + 8192), "v"((u32)hl) : "memory");
      }
    }
    __syncthreads();  // all emits drained
    if (tid == 0) {  // clean release: nothing else outstanding in this wave
      if constexpr (COH != 0) st_plain(flags + dir * 32 + sub, t + 2 + GB);
      else st_cc(flags + dir * 32 + sub, t + 2 + GB);
    }
    // next step's xg prefetch: issued AFTER release (R10 lesson); drains in next poll
    {
      const int tn = (t + 1 < T_) ? (t + 1) : t;
      const int trn = dir ? (T_ - 1 - tn) : tn;
#pragma unroll
      for (int g = 0; g < 4; ++g) {
        const float* p = xg + (size_t)(sb * T_ + trn) * N_ + dir * 2048 + g * 512 + gu;
        asm volatile("global_load_dword %0, %1, off" : "=v"(xv[g]) : "v"(p) : "memory");
      }
    }
    hs[(size_t)((dir * 16 + sb) * T_ + trow) * 512 + gu] = h;  // off critical path
  }
}

// ---------------- persistent BiLSTM recurrence: probe-gated XCD teams (16x512 per dir) ----------------
__global__ __launch_bounds__(512, 1) void k_recur(const float* __restrict__ xg, const float* __restrict__ whh_f,
                                                  const float* __restrict__ whh_b, const float* __restrict__ h0,
                                                  const float* __restrict__ c0, float* __restrict__ hs,
                                                  u16* __restrict__ hbufA, u16* __restrict__ hbufB,
                                                  int* __restrict__ flagsA, int* __restrict__ flagsB,
                                                  int* __restrict__ probe, int* __restrict__ probe2,
                                                  int* __restrict__ ctrl) {
  __shared__ __align__(16) u16 lds_a[16384];  // 32KB h staging
  __shared__ float epil[8 * 324];
  __shared__ int s_act, s_cfg;

  const int tid = threadIdx.x;

  if (tid == 0) {
    int xcc;
    asm volatile("s_getreg_b32 %0, hwreg(HW_REG_XCC_ID)" : "=s"(xcc));
    xcc &= 7;
    int slot = 99;
    if (xcc < 2) slot = __hip_atomic_fetch_add(&ctrl[4 + xcc], 1, __ATOMIC_RELAXED, __HIP_MEMORY_SCOPE_AGENT);
    const int roleA = (xcc < 2 && slot < 16);
    const int dir = xcc, sub = slot;
    // flag milestones: 2 arrived / 3 A-ok / 4 r1-ok / 5 r2-armed / 6 FAST-ok / 7,8 fail. All < 10.
    if (roleA) {
      int* myflag = flagsA + dir * 32 + sub;
      const int fb = dir * 32;
      int mg = MAGIC_;
      asm volatile("global_store_dword %0, %1, off\n\ts_waitcnt vmcnt(0)" :: "v"(probe + fb + sub), "v"(mg) : "memory");
      st_cc(myflag, 2);
      bool complete = false;
      for (int it = 0; it < POLL_BUDGET && !complete; ++it) {
        complete = true;
        for (int j = 0; j < 16; ++j)
          if (ld_cc(flagsA + fb + j) < 2) { complete = false; break; }
        if (!complete) __builtin_amdgcn_s_sleep(16);
      }
      bool Aok = complete;
      if (Aok)
        for (int j = 0; j < 16; ++j)
          if (ld_cc(probe + fb + j) != MAGIC_) { Aok = false; break; }
      if (Aok) {
        int m2 = MAGIC2_;
        asm volatile("global_store_dword %0, %1, off\n\ts_waitcnt vmcnt(0)" :: "v"(probe2 + fb + sub), "v"(m2) : "memory");
      }
      st_cc(myflag, Aok ? 3 : 7);
      bool any7 = !Aok, arrived = false;
      for (int it = 0; it < PHB_BUDGET && !arrived && !any7; ++it) {
        arrived = true;
        for (int j = 0; j < 16; ++j) {
          int f = ld_cc(flagsA + fb + j);
          if (f == 7) { any7 = true; break; }
          if (f < 3) { arrived = false; break; }
        }
        if (!arrived && !any7) __builtin_amdgcn_s_sleep(4);
      }
      if (Aok && arrived && !any7) {
        bool r1 = true;
        for (int j = 0; j < 16; ++j)
          if (ld_se(probe2 + fb + j) != MAGIC2_) { r1 = false; break; }
        st_cc(myflag, r1 ? 4 : 8);
        if (r1) {
          bool all4 = false, any8 = false;
          for (int it = 0; it < PHB_BUDGET && !all4 && !any8; ++it) {
            all4 = true;
            for (int j = 0; j < 16; ++j) {
              int f = ld_cc(flagsA + fb + j);
              if (f == 8) { any8 = true; break; }
              if (f < 4) { all4 = false; break; }
            }
            if (!all4 && !any8) __builtin_amdgcn_s_sleep(4);
          }
          if (all4 && !any8) {
            int m3 = MAGIC3_;
            asm volatile("global_store_dword %0, %1, off\n\ts_waitcnt vmcnt(0)" :: "v"(probe2 + fb + sub), "v"(m3) : "memory");
            st_cc(myflag, 5);
            bool all5 = false;
            for (int it = 0; it < PHB_BUDGET && !all5; ++it) {
              all5 = true;
              for (int j = 0; j < 16; ++j)
                if (ld_cc(flagsA + fb + j) < 5) { all5 = false; break; }
              if (!all5) __builtin_amdgcn_s_sleep(4);
            }
            bool r2 = all5;
            if (r2)
              for (int j = 0; j < 16; ++j)
                if (ld_se(probe2 + fb + j) != MAGIC3_) { r2 = false; break; }
            st_cc(myflag, r2 ? 6 : 8);
          }
        }
      }
      if (sub == 0) {  // decider: FAST(3) iff all 16 reach 6; MID(1) if A passed; else FALLBACK(2)
        int verdict = Aok ? 1 : 2;
        for (int it = 0; it < PHB_BUDGET; ++it) {
          int n6 = 0;
          bool bad7 = false, bad8 = false, pending = false;
          for (int j = 0; j < 16; ++j) {
            int f = ld_cc(flagsA + fb + j);
            if (f == 7) { bad7 = true; break; }
            if (f == 8) { bad8 = true; break; }
            if (f == 6) ++n6;
            else pending = true;
          }
          if (bad7) { verdict = 2; break; }
          if (bad8) { verdict = Aok ? 1 : 2; break; }
          if (n6 == 16) { verdict = 3; break; }
          if (pending) __builtin_amdgcn_s_sleep(4);
        }
        st_cc(&ctrl[12 + dir], verdict);
      }
    }

    if (blockIdx.x == 0) {  // arbiter
      int v0 = 0, v1 = 0;
      for (int it = 0; it < ARB_BUDGET; ++it) {
        v0 = ld_cc(&ctrl[12]);
        v1 = ld_cc(&ctrl[13]);
        if (v0 && v1) break;
        __builtin_amdgcn_s_sleep(16);
      }
      if (!v0) v0 = 2;
      if (!v1) v1 = 2;
      st_cc(&ctrl[14], 0x100 | v0 | (v1 << 4));
    }

    int cfg;
    do {
      cfg = ld_cc(&ctrl[14]);
      if (!cfg) __builtin_amdgcn_s_sleep(16);
    } while (!cfg);

    s_cfg = cfg;
    int md = (cfg >> (dir * 4)) & 15;
    s_act = (roleA && md != 2) ? (dir | (sub << 1) | (md << 6)) : -1;
  }
  __syncthreads();
  const int act = s_act, cfg = s_cfg;

  if (act >= 0) {
    const int adir = act & 1, asub = (act >> 1) & 31, md = act >> 6;
    if (md == 3)
      run_recur<2>(adir, asub, xg, adir ? whh_b : whh_f, h0, c0, hs, hbufA, flagsA, lds_a, epil);
    else
      run_recur<1>(adir, asub, xg, adir ? whh_b : whh_f, h0, c0, hs, hbufA, flagsA, lds_a, epil);
  }
  if (blockIdx.x < 32) {  // fallback duty for any dir in FALLBACK mode (16 blocks/dir)
    const int mdir = (int)blockIdx.x >> 4, msub = (int)blockIdx.x & 15;
    if (((cfg >> (mdir * 4)) & 15) == 2)
      run_recur<0>(mdir, msub, xg, mdir ? whh_b : whh_f, h0, c0, hs, hbufB, flagsB, lds_a, epil);
  }
}

// ---------------- emissions: e = [hf|hb] @ w_out + b_out ----------------
__global__ __launch_bounds__(256) void k_emis(const float* __restrict__ hs, const float* __restrict__ wout,
                                              const float* __restrict__ bout, float* __restrict__ e) {
  const int tid = threadIdx.x;
  const int w = tid >> 6, l = tid & 63;
  const int row = blockIdx.x * 4 + w;  // < 8160
  const int b = row / T_, t = row - b * T_;
  const float* hf = hs + (size_t)(b * T_ + t) * 512;
  const float* hb = hs + (size_t)((16 + b) * T_ + t) * 512;
  float a0 = 0, a1 = 0, a2 = 0, a3 = 0, a4 = 0;
#pragma unroll
  for (int it = 0; it < 8; ++it) {
    int u = it * 64 + l;
    float hv = hf[u];
    const float* wr = wout + u * 5;
    a0 += hv * wr[0]; a1 += hv * wr[1]; a2 += hv * wr[2]; a3 += hv * wr[3]; a4 += hv * wr[4];
  }
#pragma unroll
  for (int it = 0; it < 8; ++it) {
    int u = it * 64 + l;
    float hv = hb[u];
    const float* wr = wout + (512 + u) * 5;
    a0 += hv * wr[0]; a1 += hv * wr[1]; a2 += hv * wr[2]; a3 += hv * wr[3]; a4 += hv * wr[4];
  }
  for (int off = 32; off; off >>= 1) {
    a0 += __shfl_down(a0, off);
    a1 += __shfl_down(a1, off);
    a2 += __shfl_down(a2, off);
    a3 += __shfl_down(a3, off);
    a4 += __shfl_down(a4, off);
  }
  if (l == 0) {
    float* ep = e + (size_t)row * 5;
    ep[0] = a0 + bout[0];
    ep[1] = a1 + bout[1];
    ep[2] = a2 + bout[2];
    ep[3] = a3 + bout[3];
    ep[4] = a4 + bout[4];
  }
}

// ---------------- Viterbi per batch ----------------
__global__ __launch_bounds__(64) void k_viterbi(const float* __restrict__ e, const int* __restrict__ V,
                                                const float* __restrict__ start, const float* __restrict__ endv,
                                                const float* __restrict__ trans, int* __restrict__ out) {
  __shared__ float els[T_ * 5];
  __shared__ unsigned char hist[(T_ - 1) * 5];
  __shared__ float strans[25];
  const int b = blockIdx.x, l = threadIdx.x;
  for (int i = l; i < T_ * 5; i += 64) els[i] = e[(size_t)b * T_ * 5 + i];
  if (l < 25) strans[l] = trans[l];
  const int Vb = V[b];
  __syncthreads();
  const int cl = (l < 5) ? l : 0;
  float score = (l < 5) ? (start[l] + els[l]) : -1e30f;
  for (int t = 1; t < T_; ++t) {
    const bool valid = t < Vb;
    float m = -1e30f;
    int arg = 0;
#pragma unroll
    for (int p = 0; p < 5; ++p) {
      float v = __shfl(score, p) + strans[p * 5 + cl];
      if (v > m) { m = v; arg = p; }
    }
    if (l < 5) {
      if (valid) {
        score = m + els[t * 5 + l];
        hist[(t - 1) * 5 + l] = (unsigned char)arg;
      } else {
        hist[(t - 1) * 5 + l] = (unsigned char)l;
      }
    }
  }
  float sc = (l < 5) ? (score + endv[l]) : -1e30f;
  int last = 0;
  float mb = -1e30f;
#pragma unroll
  for (int p = 0; p < 5; ++p) {
    float v = __shfl(sc, p);
    if (v > mb) { mb = v; last = p; }
  }
  __syncthreads();
  if (l == 0) {
    int tag = last;
    out[b * T_ + (T_ - 1)] = tag;
    for (int t = T_ - 2; t >= 0; --t) {
      tag = hist[t * 5 + tag];
      out[b * T_ + t] = tag;
    }
  }
}

extern "C" void kernel_launch(void* const* d_in, const int* in_sizes, int n_in, void* d_out, int out_size,
                              void* d_ws, size_t ws_size, hipStream_t stream) {
  const float* emb = (const float*)d_in[0];
  const int* amask = (const int*)d_in[1];
  const float* h0 = (const float*)d_in[2];
  const float* c0 = (const float*)d_in[3];
  const float* wihf = (const float*)d_in[4];
  const float* whhf = (const float*)d_in[5];
  const float* bihf = (const float*)d_in[6];
  const float* bhhf = (const float*)d_in[7];
  const float* wihb = (const float*)d_in[8];
  const float* whhb = (const float*)d_in[9];
  const float* bihb = (const float*)d_in[10];
  const float* bhhb = (const float*)d_in[11];
  const float* wout = (const float*)d_in[12];
  const float* bout = (const float*)d_in[13];
  const float* cstart = (const float*)d_in[14];
  const float* cend = (const float*)d_in[15];
  const float* ctrans = (const float*)d_in[16];

  char* ws = (char*)d_ws;
  u16* Abig = (u16*)(ws + OFF_ABIG);
  u16* Bbig = (u16*)(ws + OFF_BBIG);
  float* bias = (float*)(ws + OFF_BIAS);
  float* xg = (float*)(ws + OFF_XG);
  float* hs = (float*)(ws + OFF_HS);
  float* emis = (float*)(ws + OFF_EMIS);
  int* V = (int*)(ws + OFF_V);
  int* flagsA = (int*)(ws + OFF_FLAGS);
  u16* hbufA = (u16*)(ws + OFF_HBUF);
  u16* hbufB = (u16*)(ws + OFF_HBUFB);
  int* flagsB = (int*)(ws + OFF_FLAGSB);
  int* probe = (int*)(ws + OFF_PROBE);
  int* probe2 = (int*)(ws + OFF_PROBE2);
  int* ctrl = (int*)(ws + OFF_CTRL);
  int* out = (int*)d_out;

  hipLaunchKernelGGL(k_prep, dim3(16), dim3(256), 0, stream, amask, V, flagsA, flagsB, probe, probe2, ctrl);
  hipLaunchKernelGGL(k_valid, dim3(32), dim3(256), 0, stream, V, out);
  hipLaunchKernelGGL(k_splitA, dim3(8192), dim3(320), 0, stream, emb, V, Abig);
  hipLaunchKernelGGL(k_splitB, dim3(4096), dim3(320), 0, stream, wihf, wihb, bihf, bhhf, bihb, bhhb, Bbig, bias);
  hipLaunchKernelGGL(k_gemm, dim3(64, 32), dim3(256), 0, stream, Abig, Bbig, bias, xg);
  hipLaunchKernelGGL(k_recur, dim3(160), dim3(512), 0, stream, xg, whhf, whhb, h0, c0, hs, hbufA, hbufB,
                     flagsA, flagsB, probe, probe2, ctrl);
  hipLaunchKernelGGL(k_emis, dim3(2040), dim3(256), 0, stream, hs, wout, bout, emis);
  hipLaunchKernelGGL(k_viterbi, dim3(16), dim3(64), 0, stream, emis, V, cstart, cend, ctrans, out);
}

// Round 14
// 1549.111 us; speedup vs baseline: 6.8207x; 6.8207x over previous
//
#include <hip/hip_runtime.h>

typedef unsigned short u16;
typedef unsigned int u32;
typedef __bf16 bf16x8 __attribute__((ext_vector_type(8)));
typedef u16 u16x8 __attribute__((ext_vector_type(8)));
typedef float f32x4 __attribute__((ext_vector_type(4)));
typedef u32 u32x4 __attribute__((ext_vector_type(4)));

#define B_ 16
#define T_ 510
#define H_ 512
#define N_ 4096
#define KSPLIT 2560  // [hi(1280) | lo(1280)]

// workspace offsets (bytes)
#define OFF_ABIG  0ull
#define OFF_BBIG  41943040ull
#define OFF_BIAS  62914560ull
#define OFF_XG    62930944ull
#define OFF_HS    197148672ull
#define OFF_EMIS  230572032ull
#define OFF_V     230735232ull
#define OFF_FLAGS 230735296ull   // flagsA (64 ints)
#define OFF_HBUF  230735552ull   // hbufA (128KB)
// borrowed from the emissions region (written by k_emis only AFTER k_recur):
#define OFF_HBUFB  (OFF_EMIS)              // 128KB
#define OFF_FLAGSB (OFF_EMIS + 131072ull)  // 256B
#define OFF_PROBE  (OFF_EMIS + 131328ull)  // 256B
#define OFF_CTRL   (OFF_EMIS + 131584ull)  // 64B
#define OFF_PROBE2 (OFF_EMIS + 131648ull)  // 256B

#define MAGIC_  0x5EC0FFEE
#define MAGIC2_ 0x7A57C0DE
#define MAGIC3_ 0x3C0DE777
#define POLL_BUDGET 65536
#define PHB_BUDGET  8192
#define ARB_BUDGET  262144

#define GL_LDS(g, s) __builtin_amdgcn_global_load_lds(                      \
    (const __attribute__((address_space(1))) void*)(g),                     \
    (__attribute__((address_space(3))) void*)(s), 16, 0, 0)

__device__ __forceinline__ u16 f2bf(float x) {
  u32 u = __float_as_uint(x);
  u32 r = (u + 0x7fffu + ((u >> 16) & 1u)) >> 16;
  return (u16)r;
}
__device__ __forceinline__ float bf2f(u16 h) { return __uint_as_float(((u32)h) << 16); }

__device__ __forceinline__ int ld_cc(const int* p) {
  int f;
  asm volatile("global_load_dword %0, %1, off sc0 sc1\n\ts_waitcnt vmcnt(0)" : "=v"(f) : "v"(p) : "memory");
  return f;
}
__device__ __forceinline__ int ld_se(const int* p) {
  int f;
  asm volatile("global_load_dword %0, %1, off sc0\n\ts_waitcnt vmcnt(0)" : "=v"(f) : "v"(p) : "memory");
  return f;
}
__device__ __forceinline__ void st_cc(int* p, int v) {
  asm volatile("global_store_dword %0, %1, off sc0 sc1\n\ts_waitcnt vmcnt(0)" :: "v"(p), "v"(v) : "memory");
}
__device__ __forceinline__ void st_plain(int* p, int v) {
  asm volatile("global_store_dword %0, %1, off\n\ts_waitcnt vmcnt(0)" :: "v"(p), "v"(v) : "memory");
}

__device__ __forceinline__ float sigm_f(float x) {  // exact-pass verified (R7/R10/R12)
  float e = __expf(-x);
  return __builtin_amdgcn_rcpf(1.f + e);
}
__device__ __forceinline__ float tanh_f(float x) {
  float e = __expf(2.f * x);
  return 1.f - 2.f * __builtin_amdgcn_rcpf(e + 1.f);
}

// ---------------- K0: lengths + zero all protocol state ----------------
__global__ __launch_bounds__(256) void k_prep(const int* __restrict__ mask, int* __restrict__ V,
                                              int* __restrict__ flagsA, int* __restrict__ flagsB,
                                              int* __restrict__ probe, int* __restrict__ probe2,
                                              int* __restrict__ ctrl) {
  __shared__ int red[4];
  int b = blockIdx.x, tid = threadIdx.x;
  int s = mask[b * 512 + tid] + mask[b * 512 + 256 + tid];
  for (int off = 32; off; off >>= 1) s += __shfl_down(s, off);
  if ((tid & 63) == 0) red[tid >> 6] = s;
  __syncthreads();
  if (tid == 0) V[b] = red[0] + red[1] + red[2] + red[3] - 2;
  if (b == 0 && tid < 64) flagsA[tid] = 0;
  if (b == 2 && tid < 64) flagsB[tid] = 0;
  if (b == 3 && tid < 64) probe[tid] = 0;
  if (b == 4 && tid < 64) probe2[tid] = 0;
  if (b == 1 && tid < 16) ctrl[tid] = 0;
}

// ---------------- valid output ----------------
__global__ __launch_bounds__(256) void k_valid(const int* __restrict__ V, int* __restrict__ out) {
  int idx = blockIdx.x * 256 + threadIdx.x;
  if (idx < B_ * T_) {
    int b = idx / T_, t = idx - b * T_;
    out[B_ * T_ + idx] = (t < V[b]) ? 1 : 0;
  }
}

// ---------------- split x into [hi|lo] bf16, masked ----------------
__global__ __launch_bounds__(320) void k_splitA(const float* __restrict__ emb, const int* __restrict__ V,
                                                u16* __restrict__ Abig) {
  int row = blockIdx.x;
  int k0 = threadIdx.x * 4;
  u16* dst = Abig + (size_t)row * KSPLIT;
  float4 v = {0.f, 0.f, 0.f, 0.f};
  if (row < B_ * T_) {
    int b = row / T_, t = row - b * T_;
    if (t < V[b]) v = *(const float4*)(emb + (size_t)(b * 512 + t + 1) * 1280 + k0);
  }
  float vs[4] = {v.x, v.y, v.z, v.w};
  ushort4 hi, lo;
  u16 h0_ = f2bf(vs[0]); u16 l0_ = f2bf(vs[0] - bf2f(h0_));
  u16 h1_ = f2bf(vs[1]); u16 l1_ = f2bf(vs[1] - bf2f(h1_));
  u16 h2_ = f2bf(vs[2]); u16 l2_ = f2bf(vs[2] - bf2f(h2_));
  u16 h3_ = f2bf(vs[3]); u16 l3_ = f2bf(vs[3] - bf2f(h3_));
  hi.x = h0_; hi.y = h1_; hi.z = h2_; hi.w = h3_;
  lo.x = l0_; lo.y = l1_; lo.z = l2_; lo.w = l3_;
  *(ushort4*)(dst + k0) = hi;
  *(ushort4*)(dst + 1280 + k0) = lo;
}

// ---------------- split W_ih into [hi|lo] bf16 (B^T layout) + bias ----------------
__global__ __launch_bounds__(320) void k_splitB(const float* __restrict__ wf, const float* __restrict__ wb,
                                                const float* __restrict__ bihf, const float* __restrict__ bhhf,
                                                const float* __restrict__ bihb, const float* __restrict__ bhhb,
                                                u16* __restrict__ Bbig, float* __restrict__ bias) {
  int n = blockIdx.x;  // 0..4095
  int k0 = threadIdx.x * 4;
  int d = n >> 11, g = n & 2047;
  const float* w = (d ? wb : wf) + (size_t)g * 1280;
  float4 v = *(const float4*)(w + k0);
  float vs[4] = {v.x, v.y, v.z, v.w};
  ushort4 hi, lo;
  u16 h0_ = f2bf(vs[0]); u16 l0_ = f2bf(vs[0] - bf2f(h0_));
  u16 h1_ = f2bf(vs[1]); u16 l1_ = f2bf(vs[1] - bf2f(h1_));
  u16 h2_ = f2bf(vs[2]); u16 l2_ = f2bf(vs[2] - bf2f(h2_));
  u16 h3_ = f2bf(vs[3]); u16 l3_ = f2bf(vs[3] - bf2f(h3_));
  hi.x = h0_; hi.y = h1_; hi.z = h2_; hi.w = h3_;
  lo.x = l0_; lo.y = l1_; lo.z = l2_; lo.w = l3_;
  u16* dst = Bbig + (size_t)n * KSPLIT;
  *(ushort4*)(dst + k0) = hi;
  *(ushort4*)(dst + 1280 + k0) = lo;
  if (threadIdx.x == 0) bias[n] = d ? (bihb[g] + bhhb[g]) : (bihf[g] + bhhf[g]);
}

// ---------------- Phase A GEMM: C[8192x4096] = Abig * Bbig^T (bf16x3, logical K=3840) ----------------
// R14: XCD-aware block swizzle (2048 blocks, 2048%8==0 -> simple bijective remap) for L2 locality.
__global__ __launch_bounds__(256, 2) void k_gemm(const u16* __restrict__ A, const u16* __restrict__ Bt,
                                                 const float* __restrict__ bias, float* __restrict__ C) {
  __shared__ __align__(16) u16 As[128 * 64];
  __shared__ __align__(16) u16 Bs[128 * 64];
  const int tid = threadIdx.x;
  const int w = tid >> 6, l = tid & 63;
  const int wm = w >> 1, wn = w & 1;
  const int bid = blockIdx.x;
  const int swz = (bid & 7) * 256 + (bid >> 3);  // XCD-contiguous chunks
  const int bm = swz >> 5, bn = swz & 31;
  f32x4 acc[4][4];
#pragma unroll
  for (int m = 0; m < 4; ++m)
#pragma unroll
    for (int n = 0; n < 4; ++n) acc[m][n] = (f32x4){0.f, 0.f, 0.f, 0.f};

  const int rQ = tid >> 3;
  const int cB = (tid & 7) * 16;
  const char* gA = (const char*)(A + (size_t)(bm * 128) * KSPLIT) + cB;
  const char* gB = (const char*)(Bt + (size_t)(bn * 128) * KSPLIT) + cB;

  for (int kt = 0; kt < 60; ++kt) {
    const int s = kt / 20, ks = kt - s * 20;
    const int aOff = ((s == 2) ? 1280 : 0) + ks * 64;
    const int bOff = ((s == 1) ? 1280 : 0) + ks * 64;
    __syncthreads();
#pragma unroll
    for (int q = 0; q < 4; ++q) {
      GL_LDS(gA + ((size_t)(q * 32 + rQ) * KSPLIT + aOff) * 2, (char*)As + q * 4096 + tid * 16);
      GL_LDS(gB + ((size_t)(q * 32 + rQ) * KSPLIT + bOff) * 2, (char*)Bs + q * 4096 + tid * 16);
    }
    __syncthreads();
#pragma unroll
    for (int kc = 0; kc < 2; ++kc) {
      bf16x8 af[4], bfr[4];
      const int kByte = kc * 64 + (l >> 4) * 16;
#pragma unroll
      for (int m = 0; m < 4; ++m)
        af[m] = *(const bf16x8*)((const char*)As + (wm * 64 + m * 16 + (l & 15)) * 128 + kByte);
#pragma unroll
      for (int n = 0; n < 4; ++n)
        bfr[n] = *(const bf16x8*)((const char*)Bs + (wn * 64 + n * 16 + (l & 15)) * 128 + kByte);
#pragma unroll
      for (int m = 0; m < 4; ++m)
#pragma unroll
        for (int n = 0; n < 4; ++n)
          acc[m][n] = __builtin_amdgcn_mfma_f32_16x16x32_bf16(af[m], bfr[n], acc[m][n], 0, 0, 0);
    }
  }
#pragma unroll
  for (int n = 0; n < 4; ++n) {
    const int gc = bn * 128 + wn * 64 + n * 16 + (l & 15);
    const float bv = bias[gc];
#pragma unroll
    for (int m = 0; m < 4; ++m) {
      const int gr0 = bm * 128 + wm * 64 + m * 16 + (l >> 4) * 4;
#pragma unroll
      for (int r = 0; r < 4; ++r) C[(size_t)(gr0 + r) * N_ + gc] = acc[m][n][r] + bv;
    }
  }
}

// ---------------- recurrence body (R12-verified; 32 blocks x 256 thr per dir) ----------------
// COH=2 FAST: plain stores (L2-dirty) + sc0 loads; poll has sc0sc1 liveness escape each 256 iters.
// COH=1 MID : plain stores + sc0sc1 loads. COH=0: cross-XCD fallback.
// Formation flag values are 2..8 < GB+1=10, so step polls (>= t+1+GB) never false-trigger.
// R10 lesson: xg prefetch at TOP of loop (after previous release). R11/R13 lesson: 256-thr
// blocks only (512-thr blocks cap VGPR at 128 on this toolchain -> weight-cache spill).
template <int COH>
__device__ void run_recur(int dir, int sub, const float* __restrict__ xg, const float* __restrict__ whh,
                          const float* __restrict__ h0, const float* __restrict__ c0,
                          float* __restrict__ hs, u16* __restrict__ hbuf, int* __restrict__ flags,
                          u16* lds_a, float* epil, float* hsh) {
  const int tid = threadIdx.x;
  const int w = tid >> 6, l = tid & 63;
  const int c = l & 15, kg = l >> 4;
  const int gate = c >> 2, uloc = c & 3;
  const int ug = sub * 16 + w * 4 + uloc;
  constexpr int GB = (COH != 0) ? 9 : 0;

  __syncthreads();  // safe re-entry

  // preload W_hh fragments, split bf16 hi/lo (held in VGPRs)
  bf16x8 whi[16], wlo[16];
  {
    const float* wrow = whh + (size_t)(gate * 512 + ug) * 512 + kg * 8;
#pragma unroll
    for (int kc = 0; kc < 16; ++kc) {
      float4 v0 = *(const float4*)(wrow + kc * 32);
      float4 v1 = *(const float4*)(wrow + kc * 32 + 4);
      float vs[8] = {v0.x, v0.y, v0.z, v0.w, v1.x, v1.y, v1.z, v1.w};
      u16x8 hi, lo;
#pragma unroll
      for (int j = 0; j < 8; ++j) {
        u16 h = f2bf(vs[j]);
        hi[j] = h;
        lo[j] = f2bf(vs[j] - bf2f(h));
      }
      whi[kc] = __builtin_bit_cast(bf16x8, hi);
      wlo[kc] = __builtin_bit_cast(bf16x8, lo);
    }
  }

  const int eb = l & 15, eu = l >> 4;
  const int eug = sub * 16 + w * 4 + eu;
  float creg = c0[(dir * 16 + eb) * 512 + eug];
  {  // publish initial h (split) into parity-0 buffer (one-time)
    float h = h0[(dir * 16 + eb) * 512 + eug];
    u16 hh = f2bf(h), hl = f2bf(h - bf2f(hh));
    size_t base = (size_t)(dir * 2) * 8192;
    u16* p0 = hbuf + base + eb * 512 + eug;
    u16* p1 = hbuf + base + 8192 + eb * 512 + eug;
    if constexpr (COH != 0) {
      asm volatile("global_store_short %0, %1, off\n\tglobal_store_short %2, %3, off\n\ts_waitcnt vmcnt(0)"
                   :: "v"(p0), "v"((u32)hh), "v"(p1), "v"((u32)hl) : "memory");
    } else {
      asm volatile("global_store_short %0, %1, off sc0 sc1\n\tglobal_store_short %2, %3, off sc0 sc1\n\ts_waitcnt vmcnt(0)"
                   :: "v"(p0), "v"((u32)hh), "v"(p1), "v"((u32)hl) : "memory");
    }
  }
  __syncthreads();
  if (tid == 0) {
    if constexpr (COH != 0) st_plain(flags + dir * 32 + sub, 1 + GB);
    else st_cc(flags + dir * 32 + sub, 1 + GB);
  }

  for (int t = 0; t < T_; ++t) {
    const int trow = dir ? (T_ - 1 - t) : t;
    // xg prefetch (top of loop = after previous release; drains inside the poll, overlapped)
    f32x4 acc0;
    {
      const int n = dir * 2048 + gate * 512 + ug;
#pragma unroll
      for (int r = 0; r < 4; ++r) acc0[r] = xg[(size_t)((kg * 4 + r) * T_ + trow) * N_ + n];
    }
    // per-dir barrier: one vectorized 32-flag poll
    if (w == 0) {
      const int* fp = flags + (dir << 5) + (l & 31);
      int it = 0;
      while (true) {
        int f;
        if constexpr (COH == 2) {
          ++it;
          if ((it & 255) == 0)
            asm volatile("global_load_dword %0, %1, off sc0 sc1\n\ts_waitcnt vmcnt(0)" : "=v"(f) : "v"(fp) : "memory");
          else
            asm volatile("global_load_dword %0, %1, off sc0\n\ts_waitcnt vmcnt(0)" : "=v"(f) : "v"(fp) : "memory");
        } else {
          asm volatile("global_load_dword %0, %1, off sc0 sc1\n\ts_waitcnt vmcnt(0)" : "=v"(f) : "v"(fp) : "memory");
        }
        if (__all(f >= t + 1 + GB)) break;
        if constexpr (COH == 0) __builtin_amdgcn_s_sleep(1);
      }
    }
    __syncthreads();

    // stage h(t) 32KB into LDS (FAST: L2-served sc0; else sc0sc1)
    {
      const u16* src = hbuf + (size_t)(((t & 1) * 2 + dir) * 2) * 8192;
      u32x4 v[8];
#pragma unroll
      for (int q = 0; q < 8; ++q) {
        const char* p = (const char*)src + q * 4096 + tid * 16;
        if constexpr (COH == 2)
          asm volatile("global_load_dwordx4 %0, %1, off sc0" : "=v"(v[q]) : "v"(p) : "memory");
        else
          asm volatile("global_load_dwordx4 %0, %1, off sc0 sc1" : "=v"(v[q]) : "v"(p) : "memory");
      }
      asm volatile("s_waitcnt vmcnt(0)" ::: "memory");
      __builtin_amdgcn_sched_barrier(0);
#pragma unroll
      for (int q = 0; q < 8; ++q) {
        int off = q * 4096 + tid * 16;
        int var = off >> 14;
        int rem = off & 16383;
        int b = rem >> 10;
        int inrow = rem & 1023;
        *(u32x4*)((char*)lds_a + var * 16384 + b * 1024 + (inrow ^ ((b & 7) << 4))) = v[q];
      }
    }
    __syncthreads();

    // 6 independent accumulator chains
    f32x4 acc1 = (f32x4){0.f, 0.f, 0.f, 0.f};
    f32x4 acc2 = (f32x4){0.f, 0.f, 0.f, 0.f};
    f32x4 acc3 = (f32x4){0.f, 0.f, 0.f, 0.f};
    f32x4 acc4 = (f32x4){0.f, 0.f, 0.f, 0.f};
    f32x4 acc5 = (f32x4){0.f, 0.f, 0.f, 0.f};
#pragma unroll
    for (int kc = 0; kc < 16; ++kc) {
      const int rowb = l & 15;
      const int koff = (kc * 64 + kg * 16) ^ ((rowb & 7) << 4);
      bf16x8 ahi = *(const bf16x8*)((const char*)lds_a + rowb * 1024 + koff);
      bf16x8 alo = *(const bf16x8*)((const char*)lds_a + 16384 + rowb * 1024 + koff);
      if (kc & 1) {
        acc3 = __builtin_amdgcn_mfma_f32_16x16x32_bf16(ahi, whi[kc], acc3, 0, 0, 0);
        acc4 = __builtin_amdgcn_mfma_f32_16x16x32_bf16(ahi, wlo[kc], acc4, 0, 0, 0);
        acc5 = __builtin_amdgcn_mfma_f32_16x16x32_bf16(alo, whi[kc], acc5, 0, 0, 0);
      } else {
        acc0 = __builtin_amdgcn_mfma_f32_16x16x32_bf16(ahi, whi[kc], acc0, 0, 0, 0);
        acc1 = __builtin_amdgcn_mfma_f32_16x16x32_bf16(ahi, wlo[kc], acc1, 0, 0, 0);
        acc2 = __builtin_amdgcn_mfma_f32_16x16x32_bf16(alo, whi[kc], acc2, 0, 0, 0);
      }
    }
    f32x4 acc = ((acc0 + acc3) + (acc1 + acc4)) + (acc2 + acc5);

    // epilogue: transpose 16x16 via wave-private LDS (stride 20 = 2-way banks), fast gates
#pragma unroll
    for (int r = 0; r < 4; ++r) epil[(w * 16 + kg * 4 + r) * 20 + c] = acc[r];
    asm volatile("s_waitcnt lgkmcnt(0)" ::: "memory");
    __builtin_amdgcn_sched_barrier(0);
    const float gi = epil[(w * 16 + eb) * 20 + 0 + eu];
    const float gf = epil[(w * 16 + eb) * 20 + 4 + eu];
    const float gg = epil[(w * 16 + eb) * 20 + 8 + eu];
    const float go = epil[(w * 16 + eb) * 20 + 12 + eu];
    const float si = sigm_f(gi);
    const float sf = sigm_f(gf);
    const float so = sigm_f(go);
    const float tg = tanh_f(gg);
    creg = sf * creg + si * tg;
    const float h = so * tanh_f(creg);
    // redistribute h so stores are wave-contiguous
    hsh[eb * 17 + w * 4 + eu] = h;
    __syncthreads();
    const int sb = tid >> 4, su = tid & 15;
    const float hv = hsh[sb * 17 + su];
    {
      u16 hh = f2bf(hv), hl = f2bf(hv - bf2f(hh));
      size_t base = (size_t)((((t + 1) & 1) * 2 + dir) * 2) * 8192;
      u16* p0 = hbuf + base + sb * 512 + sub * 16 + su;
      if constexpr (COH != 0) {
        asm volatile("global_store_short %0, %1, off\n\tglobal_store_short %2, %3, off\n\ts_waitcnt vmcnt(0)"
                     :: "v"(p0), "v"((u32)hh), "v"(p0 + 8192), "v"((u32)hl) : "memory");
      } else {
        asm volatile("global_store_short %0, %1, off sc0 sc1\n\tglobal_store_short %2, %3, off sc0 sc1\n\ts_waitcnt vmcnt(0)"
                     :: "v"(p0), "v"((u32)hh), "v"(p0 + 8192), "v"((u32)hl) : "memory");
      }
    }
    __syncthreads();
    if (tid == 0) {  // clean release: nothing outstanding in this wave
      if constexpr (COH != 0) st_plain(flags + dir * 32 + sub, t + 2 + GB);
      else st_cc(flags + dir * 32 + sub, t + 2 + GB);
    }
    hs[(size_t)((dir * 16 + sb) * T_ + trow) * 512 + sub * 16 + su] = hv;
  }
}

// ---------------- persistent BiLSTM recurrence: probe-gated XCD teams + sc0 capability probe ----------------
__global__ __launch_bounds__(256, 1) void k_recur(const float* __restrict__ xg, const float* __restrict__ whh_f,
                                                  const float* __restrict__ whh_b, const float* __restrict__ h0,
                                                  const float* __restrict__ c0, float* __restrict__ hs,
                                                  u16* __restrict__ hbufA, u16* __restrict__ hbufB,
                                                  int* __restrict__ flagsA, int* __restrict__ flagsB,
                                                  int* __restrict__ probe, int* __restrict__ probe2,
                                                  int* __restrict__ ctrl) {
  __shared__ __align__(16) u16 lds_a[16384];
  __shared__ float epil[4 * 16 * 20];
  __shared__ float hsh[16 * 17];
  __shared__ int s_act, s_cfg;

  const int tid = threadIdx.x;

  if (tid == 0) {
    int xcc;
    asm volatile("s_getreg_b32 %0, hwreg(HW_REG_XCC_ID)" : "=s"(xcc));
    xcc &= 7;
    int slot = 99;
    if (xcc < 2) slot = __hip_atomic_fetch_add(&ctrl[4 + xcc], 1, __ATOMIC_RELAXED, __HIP_MEMORY_SCOPE_AGENT);
    const int roleA = (xcc < 2 && slot < 32);
    const int dir = xcc, sub = slot;
    // flag milestones: 2 arrived / 3 A-ok / 4 r1-ok / 5 r2-armed / 6 FAST-ok / 7,8 fail. All < 10.
    if (roleA) {
      int* myflag = flagsA + dir * 32 + sub;
      const int fb = dir * 32;
      int mg = MAGIC_;
      asm volatile("global_store_dword %0, %1, off\n\ts_waitcnt vmcnt(0)" :: "v"(probe + fb + sub), "v"(mg) : "memory");
      st_cc(myflag, 2);
      bool complete = false;
      for (int it = 0; it < POLL_BUDGET && !complete; ++it) {
        complete = true;
        for (int j = 0; j < 32; ++j)
          if (ld_cc(flagsA + fb + j) < 2) { complete = false; break; }
        if (!complete) __builtin_amdgcn_s_sleep(16);
      }
      bool Aok = complete;
      if (Aok)
        for (int j = 0; j < 32; ++j)
          if (ld_cc(probe + fb + j) != MAGIC_) { Aok = false; break; }
      if (Aok) {
        int m2 = MAGIC2_;
        asm volatile("global_store_dword %0, %1, off\n\ts_waitcnt vmcnt(0)" :: "v"(probe2 + fb + sub), "v"(m2) : "memory");
      }
      st_cc(myflag, Aok ? 3 : 7);
      bool any7 = !Aok, arrived = false;
      for (int it = 0; it < PHB_BUDGET && !arrived && !any7; ++it) {
        arrived = true;
        for (int j = 0; j < 32; ++j) {
          int f = ld_cc(flagsA + fb + j);
          if (f == 7) { any7 = true; break; }
          if (f < 3) { arrived = false; break; }
        }
        if (!arrived && !any7) __builtin_amdgcn_s_sleep(4);
      }
      if (Aok && arrived && !any7) {
        bool r1 = true;
        for (int j = 0; j < 32; ++j)
          if (ld_se(probe2 + fb + j) != MAGIC2_) { r1 = false; break; }
        st_cc(myflag, r1 ? 4 : 8);
        if (r1) {
          bool all4 = false, any8 = false;
          for (int it = 0; it < PHB_BUDGET && !all4 && !any8; ++it) {
            all4 = true;
            for (int j = 0; j < 32; ++j) {
              int f = ld_cc(flagsA + fb + j);
              if (f == 8) { any8 = true; break; }
              if (f < 4) { all4 = false; break; }
            }
            if (!all4 && !any8) __builtin_amdgcn_s_sleep(4);
          }
          if (all4 && !any8) {
            int m3 = MAGIC3_;
            asm volatile("global_store_dword %0, %1, off\n\ts_waitcnt vmcnt(0)" :: "v"(probe2 + fb + sub), "v"(m3) : "memory");
            st_cc(myflag, 5);
            bool all5 = false;
            for (int it = 0; it < PHB_BUDGET && !all5; ++it) {
              all5 = true;
              for (int j = 0; j < 32; ++j)
                if (ld_cc(flagsA + fb + j) < 5) { all5 = false; break; }
              if (!all5) __builtin_amdgcn_s_sleep(4);
            }
            bool r2 = all5;
            if (r2)
              for (int j = 0; j < 32; ++j)
                if (ld_se(probe2 + fb + j) != MAGIC3_) { r2 = false; break; }
            st_cc(myflag, r2 ? 6 : 8);
          }
        }
      }
      if (sub == 0) {
        int verdict = Aok ? 1 : 2;
        for (int it = 0; it < PHB_BUDGET; ++it) {
          int n6 = 0;
          bool bad7 = false, bad8 = false, pending = false;
          for (int j = 0; j < 32; ++j) {
            int f = ld_cc(flagsA + fb + j);
            if (f == 7) { bad7 = true; break; }
            if (f == 8) { bad8 = true; break; }
            if (f == 6) ++n6;
            else pending = true;
          }
          if (bad7) { verdict = 2; break; }
          if (bad8) { verdict = Aok ? 1 : 2; break; }
          if (n6 == 32) { verdict = 3; break; }
          if (pending) __builtin_amdgcn_s_sleep(4);
        }
        st_cc(&ctrl[12 + dir], verdict);
      }
    }

    if (blockIdx.x == 0) {  // arbiter
      int v0 = 0, v1 = 0;
      for (int it = 0; it < ARB_BUDGET; ++it) {
        v0 = ld_cc(&ctrl[12]);
        v1 = ld_cc(&ctrl[13]);
        if (v0 && v1) break;
        __builtin_amdgcn_s_sleep(16);
      }
      if (!v0) v0 = 2;
      if (!v1) v1 = 2;
      st_cc(&ctrl[14], 0x100 | v0 | (v1 << 4));
    }

    int cfg;
    do {
      cfg = ld_cc(&ctrl[14]);
      if (!cfg) __builtin_amdgcn_s_sleep(16);
    } while (!cfg);

    s_cfg = cfg;
    int md = (cfg >> (dir * 4)) & 15;
    s_act = (roleA && md != 2) ? (dir | (sub << 1) | (md << 6)) : -1;
  }
  __syncthreads();
  const int act = s_act, cfg = s_cfg;

  if (act >= 0) {
    const int adir = act & 1, asub = (act >> 1) & 31, md = act >> 6;
    if (md == 3)
      run_recur<2>(adir, asub, xg, adir ? whh_b : whh_f, h0, c0, hs, hbufA, flagsA, lds_a, epil, hsh);
    else
      run_recur<1>(adir, asub, xg, adir ? whh_b : whh_f, h0, c0, hs, hbufA, flagsA, lds_a, epil, hsh);
  }
  if (blockIdx.x < 64) {  // fallback duty for any dir in FALLBACK mode
    const int mdir = (int)blockIdx.x >> 5, msub = (int)blockIdx.x & 31;
    if (((cfg >> (mdir * 4)) & 15) == 2)
      run_recur<0>(mdir, msub, xg, mdir ? whh_b : whh_f, h0, c0, hs, hbufB, flagsB, lds_a, epil, hsh);
  }
}

// ---------------- emissions: e = [hf|hb] @ w_out + b_out ----------------
__global__ __launch_bounds__(256) void k_emis(const float* __restrict__ hs, const float* __restrict__ wout,
                                              const float* __restrict__ bout, float* __restrict__ e) {
  const int tid = threadIdx.x;
  const int w = tid >> 6, l = tid & 63;
  const int row = blockIdx.x * 4 + w;  // < 8160
  const int b = row / T_, t = row - b * T_;
  const float* hf = hs + (size_t)(b * T_ + t) * 512;
  const float* hb = hs + (size_t)((16 + b) * T_ + t) * 512;
  float a0 = 0, a1 = 0, a2 = 0, a3 = 0, a4 = 0;
#pragma unroll
  for (int it = 0; it < 8; ++it) {
    int u = it * 64 + l;
    float hv = hf[u];
    const float* wr = wout + u * 5;
    a0 += hv * wr[0]; a1 += hv * wr[1]; a2 += hv * wr[2]; a3 += hv * wr[3]; a4 += hv * wr[4];
  }
#pragma unroll
  for (int it = 0; it < 8; ++it) {
    int u = it * 64 + l;
    float hv = hb[u];
    const float* wr = wout + (512 + u) * 5;
    a0 += hv * wr[0]; a1 += hv * wr[1]; a2 += hv * wr[2]; a3 += hv * wr[3]; a4 += hv * wr[4];
  }
  for (int off = 32; off; off >>= 1) {
    a0 += __shfl_down(a0, off);
    a1 += __shfl_down(a1, off);
    a2 += __shfl_down(a2, off);
    a3 += __shfl_down(a3, off);
    a4 += __shfl_down(a4, off);
  }
  if (l == 0) {
    float* ep = e + (size_t)row * 5;
    ep[0] = a0 + bout[0];
    ep[1] = a1 + bout[1];
    ep[2] = a2 + bout[2];
    ep[3] = a3 + bout[3];
    ep[4] = a4 + bout[4];
  }
}

// ---------------- Viterbi per batch ----------------
__global__ __launch_bounds__(64) void k_viterbi(const float* __restrict__ e, const int* __restrict__ V,
                                                const float* __restrict__ start, const float* __restrict__ endv,
                                                const float* __restrict__ trans, int* __restrict__ out) {
  __shared__ float els[T_ * 5];
  __shared__ unsigned char hist[(T_ - 1) * 5];
  __shared__ float strans[25];
  const int b = blockIdx.x, l = threadIdx.x;
  for (int i = l; i < T_ * 5; i += 64) els[i] = e[(size_t)b * T_ * 5 + i];
  if (l < 25) strans[l] = trans[l];
  const int Vb = V[b];
  __syncthreads();
  const int cl = (l < 5) ? l : 0;
  float score = (l < 5) ? (start[l] + els[l]) : -1e30f;
  for (int t = 1; t < T_; ++t) {
    const bool valid = t < Vb;
    float m = -1e30f;
    int arg = 0;
#pragma unroll
    for (int p = 0; p < 5; ++p) {
      float v = __shfl(score, p) + strans[p * 5 + cl];
      if (v > m) { m = v; arg = p; }
    }
    if (l < 5) {
      if (valid) {
        score = m + els[t * 5 + l];
        hist[(t - 1) * 5 + l] = (unsigned char)arg;
      } else {
        hist[(t - 1) * 5 + l] = (unsigned char)l;
      }
    }
  }
  float sc = (l < 5) ? (score + endv[l]) : -1e30f;
  int last = 0;
  float mb = -1e30f;
#pragma unroll
  for (int p = 0; p < 5; ++p) {
    float v = __shfl(sc, p);
    if (v > mb) { mb = v; last = p; }
  }
  __syncthreads();
  if (l == 0) {
    int tag = last;
    out[b * T_ + (T_ - 1)] = tag;
    for (int t = T_ - 2; t >= 0; --t) {
      tag = hist[t * 5 + tag];
      out[b * T_ + t] = tag;
    }
  }
}

extern "C" void kernel_launch(void* const* d_in, const int* in_sizes, int n_in, void* d_out, int out_size,
                              void* d_ws, size_t ws_size, hipStream_t stream) {
  const float* emb = (const float*)d_in[0];
  const int* amask = (const int*)d_in[1];
  const float* h0 = (const float*)d_in[2];
  const float* c0 = (const float*)d_in[3];
  const float* wihf = (const float*)d_in[4];
  const float* whhf = (const float*)d_in[5];
  const float* bihf = (const float*)d_in[6];
  const float* bhhf = (const float*)d_in[7];
  const float* wihb = (const float*)d_in[8];
  const float* whhb = (const float*)d_in[9];
  const float* bihb = (const float*)d_in[10];
  const float* bhhb = (const float*)d_in[11];
  const float* wout = (const float*)d_in[12];
  const float* bout = (const float*)d_in[13];
  const float* cstart = (const float*)d_in[14];
  const float* cend = (const float*)d_in[15];
  const float* ctrans = (const float*)d_in[16];

  char* ws = (char*)d_ws;
  u16* Abig = (u16*)(ws + OFF_ABIG);
  u16* Bbig = (u16*)(ws + OFF_BBIG);
  float* bias = (float*)(ws + OFF_BIAS);
  float* xg = (float*)(ws + OFF_XG);
  float* hs = (float*)(ws + OFF_HS);
  float* emis = (float*)(ws + OFF_EMIS);
  int* V = (int*)(ws + OFF_V);
  int* flagsA = (int*)(ws + OFF_FLAGS);
  u16* hbufA = (u16*)(ws + OFF_HBUF);
  u16* hbufB = (u16*)(ws + OFF_HBUFB);
  int* flagsB = (int*)(ws + OFF_FLAGSB);
  int* probe = (int*)(ws + OFF_PROBE);
  int* probe2 = (int*)(ws + OFF_PROBE2);
  int* ctrl = (int*)(ws + OFF_CTRL);
  int* out = (int*)d_out;

  hipLaunchKernelGGL(k_prep, dim3(16), dim3(256), 0, stream, amask, V, flagsA, flagsB, probe, probe2, ctrl);
  hipLaunchKernelGGL(k_valid, dim3(32), dim3(256), 0, stream, V, out);
  hipLaunchKernelGGL(k_splitA, dim3(8192), dim3(320), 0, stream, emb, V, Abig);
  hipLaunchKernelGGL(k_splitB, dim3(4096), dim3(320), 0, stream, wihf, wihb, bihf, bhhf, bihb, bhhb, Bbig, bias);
  hipLaunchKernelGGL(k_gemm, dim3(2048), dim3(256), 0, stream, Abig, Bbig, bias, xg);
  hipLaunchKernelGGL(k_recur, dim3(256), dim3(256), 0, stream, xg, whhf, whhb, h0, c0, hs, hbufA, hbufB,
                     flagsA, flagsB, probe, probe2, ctrl);
  hipLaunchKernelGGL(k_emis, dim3(2040), dim3(256), 0, stream, hs, wout, bout, emis);
  hipLaunchKernelGGL(k_viterbi, dim3(16), dim3(64), 0, stream, emis, V, cstart, cend, ctrans, out);
}

// Round 15
// 1531.501 us; speedup vs baseline: 6.8992x; 1.0115x over previous
//
#include <hip/hip_runtime.h>

typedef unsigned short u16;
typedef unsigned int u32;
typedef __bf16 bf16x8 __attribute__((ext_vector_type(8)));
typedef u16 u16x8 __attribute__((ext_vector_type(8)));
typedef float f32x4 __attribute__((ext_vector_type(4)));
typedef u32 u32x4 __attribute__((ext_vector_type(4)));

#define B_ 16
#define T_ 510
#define H_ 512
#define N_ 4096
#define KSPLIT 2560  // [hi(1280) | lo(1280)]

// workspace offsets (bytes)
#define OFF_ABIG  0ull
#define OFF_BBIG  41943040ull
#define OFF_BIAS  62914560ull
#define OFF_XG    62930944ull
#define OFF_HS    197148672ull
#define OFF_EMIS  230572032ull
#define OFF_V     230735232ull
#define OFF_FLAGS 230735296ull   // flagsA (64 ints)
#define OFF_HBUF  230735552ull   // hbufA (128KB)
// borrowed from the emissions region (written by k_emis only AFTER k_recur):
#define OFF_HBUFB  (OFF_EMIS)              // 128KB
#define OFF_FLAGSB (OFF_EMIS + 131072ull)  // 256B
#define OFF_PROBE  (OFF_EMIS + 131328ull)  // 256B
#define OFF_CTRL   (OFF_EMIS + 131584ull)  // 64B
#define OFF_PROBE2 (OFF_EMIS + 131648ull)  // 256B

#define MAGIC_  0x5EC0FFEE
#define MAGIC2_ 0x7A57C0DE
#define MAGIC3_ 0x3C0DE777
#define POLL_BUDGET 65536
#define PHB_BUDGET  8192
#define ARB_BUDGET  262144

#define GL_LDS(g, s) __builtin_amdgcn_global_load_lds(                      \
    (const __attribute__((address_space(1))) void*)(g),                     \
    (__attribute__((address_space(3))) void*)(s), 16, 0, 0)

__device__ __forceinline__ u16 f2bf(float x) {
  u32 u = __float_as_uint(x);
  u32 r = (u + 0x7fffu + ((u >> 16) & 1u)) >> 16;
  return (u16)r;
}
__device__ __forceinline__ float bf2f(u16 h) { return __uint_as_float(((u32)h) << 16); }

__device__ __forceinline__ int ld_cc(const int* p) {
  int f;
  asm volatile("global_load_dword %0, %1, off sc0 sc1\n\ts_waitcnt vmcnt(0)" : "=v"(f) : "v"(p) : "memory");
  return f;
}
__device__ __forceinline__ int ld_se(const int* p) {
  int f;
  asm volatile("global_load_dword %0, %1, off sc0\n\ts_waitcnt vmcnt(0)" : "=v"(f) : "v"(p) : "memory");
  return f;
}
__device__ __forceinline__ void st_cc(int* p, int v) {
  asm volatile("global_store_dword %0, %1, off sc0 sc1\n\ts_waitcnt vmcnt(0)" :: "v"(p), "v"(v) : "memory");
}
__device__ __forceinline__ void st_plain(int* p, int v) {
  asm volatile("global_store_dword %0, %1, off\n\ts_waitcnt vmcnt(0)" :: "v"(p), "v"(v) : "memory");
}

__device__ __forceinline__ float sigm_f(float x) {  // exact-pass verified (R7/R10/R12)
  float e = __expf(-x);
  return __builtin_amdgcn_rcpf(1.f + e);
}
__device__ __forceinline__ float tanh_f(float x) {
  float e = __expf(2.f * x);
  return 1.f - 2.f * __builtin_amdgcn_rcpf(e + 1.f);
}

// ---------------- K0: lengths + zero all protocol state ----------------
__global__ __launch_bounds__(256) void k_prep(const int* __restrict__ mask, int* __restrict__ V,
                                              int* __restrict__ flagsA, int* __restrict__ flagsB,
                                              int* __restrict__ probe, int* __restrict__ probe2,
                                              int* __restrict__ ctrl) {
  __shared__ int red[4];
  int b = blockIdx.x, tid = threadIdx.x;
  int s = mask[b * 512 + tid] + mask[b * 512 + 256 + tid];
  for (int off = 32; off; off >>= 1) s += __shfl_down(s, off);
  if ((tid & 63) == 0) red[tid >> 6] = s;
  __syncthreads();
  if (tid == 0) V[b] = red[0] + red[1] + red[2] + red[3] - 2;
  if (b == 0 && tid < 64) flagsA[tid] = 0;
  if (b == 2 && tid < 64) flagsB[tid] = 0;
  if (b == 3 && tid < 64) probe[tid] = 0;
  if (b == 4 && tid < 64) probe2[tid] = 0;
  if (b == 1 && tid < 16) ctrl[tid] = 0;
}

// ---------------- valid output ----------------
__global__ __launch_bounds__(256) void k_valid(const int* __restrict__ V, int* __restrict__ out) {
  int idx = blockIdx.x * 256 + threadIdx.x;
  if (idx < B_ * T_) {
    int b = idx / T_, t = idx - b * T_;
    out[B_ * T_ + idx] = (t < V[b]) ? 1 : 0;
  }
}

// ---------------- split x into [hi|lo] bf16, masked ----------------
__global__ __launch_bounds__(320) void k_splitA(const float* __restrict__ emb, const int* __restrict__ V,
                                                u16* __restrict__ Abig) {
  int row = blockIdx.x;
  int k0 = threadIdx.x * 4;
  u16* dst = Abig + (size_t)row * KSPLIT;
  float4 v = {0.f, 0.f, 0.f, 0.f};
  if (row < B_ * T_) {
    int b = row / T_, t = row - b * T_;
    if (t < V[b]) v = *(const float4*)(emb + (size_t)(b * 512 + t + 1) * 1280 + k0);
  }
  float vs[4] = {v.x, v.y, v.z, v.w};
  ushort4 hi, lo;
  u16 h0_ = f2bf(vs[0]); u16 l0_ = f2bf(vs[0] - bf2f(h0_));
  u16 h1_ = f2bf(vs[1]); u16 l1_ = f2bf(vs[1] - bf2f(h1_));
  u16 h2_ = f2bf(vs[2]); u16 l2_ = f2bf(vs[2] - bf2f(h2_));
  u16 h3_ = f2bf(vs[3]); u16 l3_ = f2bf(vs[3] - bf2f(h3_));
  hi.x = h0_; hi.y = h1_; hi.z = h2_; hi.w = h3_;
  lo.x = l0_; lo.y = l1_; lo.z = l2_; lo.w = l3_;
  *(ushort4*)(dst + k0) = hi;
  *(ushort4*)(dst + 1280 + k0) = lo;
}

// ---------------- split W_ih into [hi|lo] bf16 (B^T layout) + bias ----------------
__global__ __launch_bounds__(320) void k_splitB(const float* __restrict__ wf, const float* __restrict__ wb,
                                                const float* __restrict__ bihf, const float* __restrict__ bhhf,
                                                const float* __restrict__ bihb, const float* __restrict__ bhhb,
                                                u16* __restrict__ Bbig, float* __restrict__ bias) {
  int n = blockIdx.x;  // 0..4095
  int k0 = threadIdx.x * 4;
  int d = n >> 11, g = n & 2047;
  const float* w = (d ? wb : wf) + (size_t)g * 1280;
  float4 v = *(const float4*)(w + k0);
  float vs[4] = {v.x, v.y, v.z, v.w};
  ushort4 hi, lo;
  u16 h0_ = f2bf(vs[0]); u16 l0_ = f2bf(vs[0] - bf2f(h0_));
  u16 h1_ = f2bf(vs[1]); u16 l1_ = f2bf(vs[1] - bf2f(h1_));
  u16 h2_ = f2bf(vs[2]); u16 l2_ = f2bf(vs[2] - bf2f(h2_));
  u16 h3_ = f2bf(vs[3]); u16 l3_ = f2bf(vs[3] - bf2f(h3_));
  hi.x = h0_; hi.y = h1_; hi.z = h2_; hi.w = h3_;
  lo.x = l0_; lo.y = l1_; lo.z = l2_; lo.w = l3_;
  u16* dst = Bbig + (size_t)n * KSPLIT;
  *(ushort4*)(dst + k0) = hi;
  *(ushort4*)(dst + 1280 + k0) = lo;
  if (threadIdx.x == 0) bias[n] = d ? (bihb[g] + bhhb[g]) : (bihf[g] + bhhf[g]);
}

// ---------------- Phase A GEMM: C[8192x4096] = Abig * Bbig^T (bf16x3, logical K=3840) ----------------
// R15: tiles whose 128 A-rows are ALL zero-padding (t >= V[b] or row >= 8160) skip the K-loop
// and write C = bias directly (bit-identical: MFMA over zero rows yields exact +0).
__global__ __launch_bounds__(256, 2) void k_gemm(const u16* __restrict__ A, const u16* __restrict__ Bt,
                                                 const float* __restrict__ bias, float* __restrict__ C,
                                                 const int* __restrict__ V) {
  __shared__ __align__(16) u16 As[128 * 64];
  __shared__ __align__(16) u16 Bs[128 * 64];
  __shared__ int s_skip;
  const int tid = threadIdx.x;
  const int w = tid >> 6, l = tid & 63;
  const int wm = w >> 1, wn = w & 1;
  const int bid = blockIdx.x;
  const int swz = (bid & 7) * 256 + (bid >> 3);  // XCD-contiguous chunks (neutral, kept)
  const int bm = swz >> 5, bn = swz & 31;

  // --- tile-validity check: is every row in [bm*128, bm*128+128) zero-padding? ---
  {
    const int r = bm * 128 + (tid & 127);
    int invalid;
    if (r >= B_ * T_) {
      invalid = 1;
    } else {
      const int b = r / T_, t = r - b * T_;
      invalid = (t >= V[b]) ? 1 : 0;
    }
    const unsigned long long m = __ballot(invalid);
    if (tid == 0) s_skip = 1;
    __syncthreads();
    if ((l == 0) && (m != ~0ull)) s_skip = 0;  // any valid lane in this wave -> no skip
    __syncthreads();
    if (s_skip) {  // fast path: C = bias for the whole 128x128 tile
      const int cc = tid & 127;
      const float bv = bias[bn * 128 + cc];
      const int rh = tid >> 7;  // 0..1
#pragma unroll
      for (int i = 0; i < 64; ++i) {
        const int rr = i * 2 + rh;
        C[(size_t)(bm * 128 + rr) * N_ + bn * 128 + cc] = bv;
      }
      return;
    }
  }

  f32x4 acc[4][4];
#pragma unroll
  for (int m = 0; m < 4; ++m)
#pragma unroll
    for (int n = 0; n < 4; ++n) acc[m][n] = (f32x4){0.f, 0.f, 0.f, 0.f};

  const int rQ = tid >> 3;
  const int cB = (tid & 7) * 16;
  const char* gA = (const char*)(A + (size_t)(bm * 128) * KSPLIT) + cB;
  const char* gB = (const char*)(Bt + (size_t)(bn * 128) * KSPLIT) + cB;

  for (int kt = 0; kt < 60; ++kt) {
    const int s = kt / 20, ks = kt - s * 20;
    const int aOff = ((s == 2) ? 1280 : 0) + ks * 64;
    const int bOff = ((s == 1) ? 1280 : 0) + ks * 64;
    __syncthreads();
#pragma unroll
    for (int q = 0; q < 4; ++q) {
      GL_LDS(gA + ((size_t)(q * 32 + rQ) * KSPLIT + aOff) * 2, (char*)As + q * 4096 + tid * 16);
      GL_LDS(gB + ((size_t)(q * 32 + rQ) * KSPLIT + bOff) * 2, (char*)Bs + q * 4096 + tid * 16);
    }
    __syncthreads();
#pragma unroll
    for (int kc = 0; kc < 2; ++kc) {
      bf16x8 af[4], bfr[4];
      const int kByte = kc * 64 + (l >> 4) * 16;
#pragma unroll
      for (int m = 0; m < 4; ++m)
        af[m] = *(const bf16x8*)((const char*)As + (wm * 64 + m * 16 + (l & 15)) * 128 + kByte);
#pragma unroll
      for (int n = 0; n < 4; ++n)
        bfr[n] = *(const bf16x8*)((const char*)Bs + (wn * 64 + n * 16 + (l & 15)) * 128 + kByte);
#pragma unroll
      for (int m = 0; m < 4; ++m)
#pragma unroll
        for (int n = 0; n < 4; ++n)
          acc[m][n] = __builtin_amdgcn_mfma_f32_16x16x32_bf16(af[m], bfr[n], acc[m][n], 0, 0, 0);
    }
  }
#pragma unroll
  for (int n = 0; n < 4; ++n) {
    const int gc = bn * 128 + wn * 64 + n * 16 + (l & 15);
    const float bv = bias[gc];
#pragma unroll
    for (int m = 0; m < 4; ++m) {
      const int gr0 = bm * 128 + wm * 64 + m * 16 + (l >> 4) * 4;
#pragma unroll
      for (int r = 0; r < 4; ++r) C[(size_t)(gr0 + r) * N_ + gc] = acc[m][n][r] + bv;
    }
  }
}

// ---------------- recurrence body (R12-verified; 32 blocks x 256 thr per dir) ----------------
// COH=2 FAST: plain stores (L2-dirty) + sc0 loads; poll has sc0sc1 liveness escape each 256 iters.
// COH=1 MID : plain stores + sc0sc1 loads. COH=0: cross-XCD fallback.
// Formation flag values are 2..8 < GB+1=10, so step polls (>= t+1+GB) never false-trigger.
// R10 lesson: xg prefetch at TOP of loop (after previous release). R11/R13 lesson: 256-thr
// blocks only (512-thr blocks cap VGPR at 128 on this toolchain -> weight-cache spill).
template <int COH>
__device__ void run_recur(int dir, int sub, const float* __restrict__ xg, const float* __restrict__ whh,
                          const float* __restrict__ h0, const float* __restrict__ c0,
                          float* __restrict__ hs, u16* __restrict__ hbuf, int* __restrict__ flags,
                          u16* lds_a, float* epil, float* hsh) {
  const int tid = threadIdx.x;
  const int w = tid >> 6, l = tid & 63;
  const int c = l & 15, kg = l >> 4;
  const int gate = c >> 2, uloc = c & 3;
  const int ug = sub * 16 + w * 4 + uloc;
  constexpr int GB = (COH != 0) ? 9 : 0;

  __syncthreads();  // safe re-entry

  // preload W_hh fragments, split bf16 hi/lo (held in VGPRs)
  bf16x8 whi[16], wlo[16];
  {
    const float* wrow = whh + (size_t)(gate * 512 + ug) * 512 + kg * 8;
#pragma unroll
    for (int kc = 0; kc < 16; ++kc) {
      float4 v0 = *(const float4*)(wrow + kc * 32);
      float4 v1 = *(const float4*)(wrow + kc * 32 + 4);
      float vs[8] = {v0.x, v0.y, v0.z, v0.w, v1.x, v1.y, v1.z, v1.w};
      u16x8 hi, lo;
#pragma unroll
      for (int j = 0; j < 8; ++j) {
        u16 h = f2bf(vs[j]);
        hi[j] = h;
        lo[j] = f2bf(vs[j] - bf2f(h));
      }
      whi[kc] = __builtin_bit_cast(bf16x8, hi);
      wlo[kc] = __builtin_bit_cast(bf16x8, lo);
    }
  }

  const int eb = l & 15, eu = l >> 4;
  const int eug = sub * 16 + w * 4 + eu;
  float creg = c0[(dir * 16 + eb) * 512 + eug];
  {  // publish initial h (split) into parity-0 buffer (one-time)
    float h = h0[(dir * 16 + eb) * 512 + eug];
    u16 hh = f2bf(h), hl = f2bf(h - bf2f(hh));
    size_t base = (size_t)(dir * 2) * 8192;
    u16* p0 = hbuf + base + eb * 512 + eug;
    u16* p1 = hbuf + base + 8192 + eb * 512 + eug;
    if constexpr (COH != 0) {
      asm volatile("global_store_short %0, %1, off\n\tglobal_store_short %2, %3, off\n\ts_waitcnt vmcnt(0)"
                   :: "v"(p0), "v"((u32)hh), "v"(p1), "v"((u32)hl) : "memory");
    } else {
      asm volatile("global_store_short %0, %1, off sc0 sc1\n\tglobal_store_short %2, %3, off sc0 sc1\n\ts_waitcnt vmcnt(0)"
                   :: "v"(p0), "v"((u32)hh), "v"(p1), "v"((u32)hl) : "memory");
    }
  }
  __syncthreads();
  if (tid == 0) {
    if constexpr (COH != 0) st_plain(flags + dir * 32 + sub, 1 + GB);
    else st_cc(flags + dir * 32 + sub, 1 + GB);
  }

  for (int t = 0; t < T_; ++t) {
    const int trow = dir ? (T_ - 1 - t) : t;
    // xg prefetch (top of loop = after previous release; drains inside the poll, overlapped)
    f32x4 acc0;
    {
      const int n = dir * 2048 + gate * 512 + ug;
#pragma unroll
      for (int r = 0; r < 4; ++r) acc0[r] = xg[(size_t)((kg * 4 + r) * T_ + trow) * N_ + n];
    }
    // per-dir barrier: one vectorized 32-flag poll
    if (w == 0) {
      const int* fp = flags + (dir << 5) + (l & 31);
      int it = 0;
      while (true) {
        int f;
        if constexpr (COH == 2) {
          ++it;
          if ((it & 255) == 0)
            asm volatile("global_load_dword %0, %1, off sc0 sc1\n\ts_waitcnt vmcnt(0)" : "=v"(f) : "v"(fp) : "memory");
          else
            asm volatile("global_load_dword %0, %1, off sc0\n\ts_waitcnt vmcnt(0)" : "=v"(f) : "v"(fp) : "memory");
        } else {
          asm volatile("global_load_dword %0, %1, off sc0 sc1\n\ts_waitcnt vmcnt(0)" : "=v"(f) : "v"(fp) : "memory");
        }
        if (__all(f >= t + 1 + GB)) break;
        if constexpr (COH == 0) __builtin_amdgcn_s_sleep(1);
      }
    }
    __syncthreads();

    // stage h(t) 32KB into LDS (FAST: L2-served sc0; else sc0sc1)
    {
      const u16* src = hbuf + (size_t)(((t & 1) * 2 + dir) * 2) * 8192;
      u32x4 v[8];
#pragma unroll
      for (int q = 0; q < 8; ++q) {
        const char* p = (const char*)src + q * 4096 + tid * 16;
        if constexpr (COH == 2)
          asm volatile("global_load_dwordx4 %0, %1, off sc0" : "=v"(v[q]) : "v"(p) : "memory");
        else
          asm volatile("global_load_dwordx4 %0, %1, off sc0 sc1" : "=v"(v[q]) : "v"(p) : "memory");
      }
      asm volatile("s_waitcnt vmcnt(0)" ::: "memory");
      __builtin_amdgcn_sched_barrier(0);
#pragma unroll
      for (int q = 0; q < 8; ++q) {
        int off = q * 4096 + tid * 16;
        int var = off >> 14;
        int rem = off & 16383;
        int b = rem >> 10;
        int inrow = rem & 1023;
        *(u32x4*)((char*)lds_a + var * 16384 + b * 1024 + (inrow ^ ((b & 7) << 4))) = v[q];
      }
    }
    __syncthreads();

    // 6 independent accumulator chains
    f32x4 acc1 = (f32x4){0.f, 0.f, 0.f, 0.f};
    f32x4 acc2 = (f32x4){0.f, 0.f, 0.f, 0.f};
    f32x4 acc3 = (f32x4){0.f, 0.f, 0.f, 0.f};
    f32x4 acc4 = (f32x4){0.f, 0.f, 0.f, 0.f};
    f32x4 acc5 = (f32x4){0.f, 0.f, 0.f, 0.f};
#pragma unroll
    for (int kc = 0; kc < 16; ++kc) {
      const int rowb = l & 15;
      const int koff = (kc * 64 + kg * 16) ^ ((rowb & 7) << 4);
      bf16x8 ahi = *(const bf16x8*)((const char*)lds_a + rowb * 1024 + koff);
      bf16x8 alo = *(const bf16x8*)((const char*)lds_a + 16384 + rowb * 1024 + koff);
      if (kc & 1) {
        acc3 = __builtin_amdgcn_mfma_f32_16x16x32_bf16(ahi, whi[kc], acc3, 0, 0, 0);
        acc4 = __builtin_amdgcn_mfma_f32_16x16x32_bf16(ahi, wlo[kc], acc4, 0, 0, 0);
        acc5 = __builtin_amdgcn_mfma_f32_16x16x32_bf16(alo, whi[kc], acc5, 0, 0, 0);
      } else {
        acc0 = __builtin_amdgcn_mfma_f32_16x16x32_bf16(ahi, whi[kc], acc0, 0, 0, 0);
        acc1 = __builtin_amdgcn_mfma_f32_16x16x32_bf16(ahi, wlo[kc], acc1, 0, 0, 0);
        acc2 = __builtin_amdgcn_mfma_f32_16x16x32_bf16(alo, whi[kc], acc2, 0, 0, 0);
      }
    }
    f32x4 acc = ((acc0 + acc3) + (acc1 + acc4)) + (acc2 + acc5);

    // epilogue: transpose 16x16 via wave-private LDS (stride 20 = 2-way banks), fast gates
#pragma unroll
    for (int r = 0; r < 4; ++r) epil[(w * 16 + kg * 4 + r) * 20 + c] = acc[r];
    asm volatile("s_waitcnt lgkmcnt(0)" ::: "memory");
    __builtin_amdgcn_sched_barrier(0);
    const float gi = epil[(w * 16 + eb) * 20 + 0 + eu];
    const float gf = epil[(w * 16 + eb) * 20 + 4 + eu];
    const float gg = epil[(w * 16 + eb) * 20 + 8 + eu];
    const float go = epil[(w * 16 + eb) * 20 + 12 + eu];
    const float si = sigm_f(gi);
    const float sf = sigm_f(gf);
    const float so = sigm_f(go);
    const float tg = tanh_f(gg);
    creg = sf * creg + si * tg;
    const float h = so * tanh_f(creg);
    // redistribute h so stores are wave-contiguous
    hsh[eb * 17 + w * 4 + eu] = h;
    __syncthreads();
    const int sb = tid >> 4, su = tid & 15;
    const float hv = hsh[sb * 17 + su];
    {
      u16 hh = f2bf(hv), hl = f2bf(hv - bf2f(hh));
      size_t base = (size_t)((((t + 1) & 1) * 2 + dir) * 2) * 8192;
      u16* p0 = hbuf + base + sb * 512 + sub * 16 + su;
      if constexpr (COH != 0) {
        asm volatile("global_store_short %0, %1, off\n\tglobal_store_short %2, %3, off\n\ts_waitcnt vmcnt(0)"
                     :: "v"(p0), "v"((u32)hh), "v"(p0 + 8192), "v"((u32)hl) : "memory");
      } else {
        asm volatile("global_store_short %0, %1, off sc0 sc1\n\tglobal_store_short %2, %3, off sc0 sc1\n\ts_waitcnt vmcnt(0)"
                     :: "v"(p0), "v"((u32)hh), "v"(p0 + 8192), "v"((u32)hl) : "memory");
      }
    }
    __syncthreads();
    if (tid == 0) {  // clean release: nothing outstanding in this wave
      if constexpr (COH != 0) st_plain(flags + dir * 32 + sub, t + 2 + GB);
      else st_cc(flags + dir * 32 + sub, t + 2 + GB);
    }
    hs[(size_t)((dir * 16 + sb) * T_ + trow) * 512 + sub * 16 + su] = hv;
  }
}

// ---------------- persistent BiLSTM recurrence: probe-gated XCD teams + sc0 capability probe ----------------
__global__ __launch_bounds__(256, 1) void k_recur(const float* __restrict__ xg, const float* __restrict__ whh_f,
                                                  const float* __restrict__ whh_b, const float* __restrict__ h0,
                                                  const float* __restrict__ c0, float* __restrict__ hs,
                                                  u16* __restrict__ hbufA, u16* __restrict__ hbufB,
                                                  int* __restrict__ flagsA, int* __restrict__ flagsB,
                                                  int* __restrict__ probe, int* __restrict__ probe2,
                                                  int* __restrict__ ctrl) {
  __shared__ __align__(16) u16 lds_a[16384];
  __shared__ float epil[4 * 16 * 20];
  __shared__ float hsh[16 * 17];
  __shared__ int s_act, s_cfg;

  const int tid = threadIdx.x;

  if (tid == 0) {
    int xcc;
    asm volatile("s_getreg_b32 %0, hwreg(HW_REG_XCC_ID)" : "=s"(xcc));
    xcc &= 7;
    int slot = 99;
    if (xcc < 2) slot = __hip_atomic_fetch_add(&ctrl[4 + xcc], 1, __ATOMIC_RELAXED, __HIP_MEMORY_SCOPE_AGENT);
    const int roleA = (xcc < 2 && slot < 32);
    const int dir = xcc, sub = slot;
    // flag milestones: 2 arrived / 3 A-ok / 4 r1-ok / 5 r2-armed / 6 FAST-ok / 7,8 fail. All < 10.
    if (roleA) {
      int* myflag = flagsA + dir * 32 + sub;
      const int fb = dir * 32;
      int mg = MAGIC_;
      asm volatile("global_store_dword %0, %1, off\n\ts_waitcnt vmcnt(0)" :: "v"(probe + fb + sub), "v"(mg) : "memory");
      st_cc(myflag, 2);
      bool complete = false;
      for (int it = 0; it < POLL_BUDGET && !complete; ++it) {
        complete = true;
        for (int j = 0; j < 32; ++j)
          if (ld_cc(flagsA + fb + j) < 2) { complete = false; break; }
        if (!complete) __builtin_amdgcn_s_sleep(16);
      }
      bool Aok = complete;
      if (Aok)
        for (int j = 0; j < 32; ++j)
          if (ld_cc(probe + fb + j) != MAGIC_) { Aok = false; break; }
      if (Aok) {
        int m2 = MAGIC2_;
        asm volatile("global_store_dword %0, %1, off\n\ts_waitcnt vmcnt(0)" :: "v"(probe2 + fb + sub), "v"(m2) : "memory");
      }
      st_cc(myflag, Aok ? 3 : 7);
      bool any7 = !Aok, arrived = false;
      for (int it = 0; it < PHB_BUDGET && !arrived && !any7; ++it) {
        arrived = true;
        for (int j = 0; j < 32; ++j) {
          int f = ld_cc(flagsA + fb + j);
          if (f == 7) { any7 = true; break; }
          if (f < 3) { arrived = false; break; }
        }
        if (!arrived && !any7) __builtin_amdgcn_s_sleep(4);
      }
      if (Aok && arrived && !any7) {
        bool r1 = true;
        for (int j = 0; j < 32; ++j)
          if (ld_se(probe2 + fb + j) != MAGIC2_) { r1 = false; break; }
        st_cc(myflag, r1 ? 4 : 8);
        if (r1) {
          bool all4 = false, any8 = false;
          for (int it = 0; it < PHB_BUDGET && !all4 && !any8; ++it) {
            all4 = true;
            for (int j = 0; j < 32; ++j) {
              int f = ld_cc(flagsA + fb + j);
              if (f == 8) { any8 = true; break; }
              if (f < 4) { all4 = false; break; }
            }
            if (!all4 && !any8) __builtin_amdgcn_s_sleep(4);
          }
          if (all4 && !any8) {
            int m3 = MAGIC3_;
            asm volatile("global_store_dword %0, %1, off\n\ts_waitcnt vmcnt(0)" :: "v"(probe2 + fb + sub), "v"(m3) : "memory");
            st_cc(myflag, 5);
            bool all5 = false;
            for (int it = 0; it < PHB_BUDGET && !all5; ++it) {
              all5 = true;
              for (int j = 0; j < 32; ++j)
                if (ld_cc(flagsA + fb + j) < 5) { all5 = false; break; }
              if (!all5) __builtin_amdgcn_s_sleep(4);
            }
            bool r2 = all5;
            if (r2)
              for (int j = 0; j < 32; ++j)
                if (ld_se(probe2 + fb + j) != MAGIC3_) { r2 = false; break; }
            st_cc(myflag, r2 ? 6 : 8);
          }
        }
      }
      if (sub == 0) {
        int verdict = Aok ? 1 : 2;
        for (int it = 0; it < PHB_BUDGET; ++it) {
          int n6 = 0;
          bool bad7 = false, bad8 = false, pending = false;
          for (int j = 0; j < 32; ++j) {
            int f = ld_cc(flagsA + fb + j);
            if (f == 7) { bad7 = true; break; }
            if (f == 8) { bad8 = true; break; }
            if (f == 6) ++n6;
            else pending = true;
          }
          if (bad7) { verdict = 2; break; }
          if (bad8) { verdict = Aok ? 1 : 2; break; }
          if (n6 == 32) { verdict = 3; break; }
          if (pending) __builtin_amdgcn_s_sleep(4);
        }
        st_cc(&ctrl[12 + dir], verdict);
      }
    }

    if (blockIdx.x == 0) {  // arbiter
      int v0 = 0, v1 = 0;
      for (int it = 0; it < ARB_BUDGET; ++it) {
        v0 = ld_cc(&ctrl[12]);
        v1 = ld_cc(&ctrl[13]);
        if (v0 && v1) break;
        __builtin_amdgcn_s_sleep(16);
      }
      if (!v0) v0 = 2;
      if (!v1) v1 = 2;
      st_cc(&ctrl[14], 0x100 | v0 | (v1 << 4));
    }

    int cfg;
    do {
      cfg = ld_cc(&ctrl[14]);
      if (!cfg) __builtin_amdgcn_s_sleep(16);
    } while (!cfg);

    s_cfg = cfg;
    int md = (cfg >> (dir * 4)) & 15;
    s_act = (roleA && md != 2) ? (dir | (sub << 1) | (md << 6)) : -1;
  }
  __syncthreads();
  const int act = s_act, cfg = s_cfg;

  if (act >= 0) {
    const int adir = act & 1, asub = (act >> 1) & 31, md = act >> 6;
    if (md == 3)
      run_recur<2>(adir, asub, xg, adir ? whh_b : whh_f, h0, c0, hs, hbufA, flagsA, lds_a, epil, hsh);
    else
      run_recur<1>(adir, asub, xg, adir ? whh_b : whh_f, h0, c0, hs, hbufA, flagsA, lds_a, epil, hsh);
  }
  if (blockIdx.x < 64) {  // fallback duty for any dir in FALLBACK mode
    const int mdir = (int)blockIdx.x >> 5, msub = (int)blockIdx.x & 31;
    if (((cfg >> (mdir * 4)) & 15) == 2)
      run_recur<0>(mdir, msub, xg, mdir ? whh_b : whh_f, h0, c0, hs, hbufB, flagsB, lds_a, epil, hsh);
  }
}

// ---------------- emissions: e = [hf|hb] @ w_out + b_out (valid rows only) ----------------
__global__ __launch_bounds__(256) void k_emis(const float* __restrict__ hs, const float* __restrict__ wout,
                                              const float* __restrict__ bout, float* __restrict__ e,
                                              const int* __restrict__ V) {
  const int tid = threadIdx.x;
  const int w = tid >> 6, l = tid & 63;
  const int row = blockIdx.x * 4 + w;  // < 8160
  const int b = row / T_, t = row - b * T_;
  if (t >= V[b]) return;  // Viterbi never reads emissions at invalid t (masked steps)
  const float* hf = hs + (size_t)(b * T_ + t) * 512;
  const float* hb = hs + (size_t)((16 + b) * T_ + t) * 512;
  float a0 = 0, a1 = 0, a2 = 0, a3 = 0, a4 = 0;
#pragma unroll
  for (int it = 0; it < 8; ++it) {
    int u = it * 64 + l;
    float hv = hf[u];
    const float* wr = wout + u * 5;
    a0 += hv * wr[0]; a1 += hv * wr[1]; a2 += hv * wr[2]; a3 += hv * wr[3]; a4 += hv * wr[4];
  }
#pragma unroll
  for (int it = 0; it < 8; ++it) {
    int u = it * 64 + l;
    float hv = hb[u];
    const float* wr = wout + (512 + u) * 5;
    a0 += hv * wr[0]; a1 += hv * wr[1]; a2 += hv * wr[2]; a3 += hv * wr[3]; a4 += hv * wr[4];
  }
  for (int off = 32; off; off >>= 1) {
    a0 += __shfl_down(a0, off);
    a1 += __shfl_down(a1, off);
    a2 += __shfl_down(a2, off);
    a3 += __shfl_down(a3, off);
    a4 += __shfl_down(a4, off);
  }
  if (l == 0) {
    float* ep = e + (size_t)row * 5;
    ep[0] = a0 + bout[0];
    ep[1] = a1 + bout[1];
    ep[2] = a2 + bout[2];
    ep[3] = a3 + bout[3];
    ep[4] = a4 + bout[4];
  }
}

// ---------------- Viterbi per batch ----------------
__global__ __launch_bounds__(64) void k_viterbi(const float* __restrict__ e, const int* __restrict__ V,
                                                const float* __restrict__ start, const float* __restrict__ endv,
                                                const float* __restrict__ trans, int* __restrict__ out) {
  __shared__ float els[T_ * 5];
  __shared__ unsigned char hist[(T_ - 1) * 5];
  __shared__ float strans[25];
  const int b = blockIdx.x, l = threadIdx.x;
  for (int i = l; i < T_ * 5; i += 64) els[i] = e[(size_t)b * T_ * 5 + i];
  if (l < 25) strans[l] = trans[l];
  const int Vb = V[b];
  __syncthreads();
  const int cl = (l < 5) ? l : 0;
  float score = (l < 5) ? (start[l] + els[l]) : -1e30f;
  for (int t = 1; t < T_; ++t) {
    const bool valid = t < Vb;
    float m = -1e30f;
    int arg = 0;
#pragma unroll
    for (int p = 0; p < 5; ++p) {
      float v = __shfl(score, p) + strans[p * 5 + cl];
      if (v > m) { m = v; arg = p; }
    }
    if (l < 5) {
      if (valid) {
        score = m + els[t * 5 + l];
        hist[(t - 1) * 5 + l] = (unsigned char)arg;
      } else {
        hist[(t - 1) * 5 + l] = (unsigned char)l;
      }
    }
  }
  float sc = (l < 5) ? (score + endv[l]) : -1e30f;
  int last = 0;
  float mb = -1e30f;
#pragma unroll
  for (int p = 0; p < 5; ++p) {
    float v = __shfl(sc, p);
    if (v > mb) { mb = v; last = p; }
  }
  __syncthreads();
  if (l == 0) {
    int tag = last;
    out[b * T_ + (T_ - 1)] = tag;
    for (int t = T_ - 2; t >= 0; --t) {
      tag = hist[t * 5 + tag];
      out[b * T_ + t] = tag;
    }
  }
}

extern "C" void kernel_launch(void* const* d_in, const int* in_sizes, int n_in, void* d_out, int out_size,
                              void* d_ws, size_t ws_size, hipStream_t stream) {
  const float* emb = (const float*)d_in[0];
  const int* amask = (const int*)d_in[1];
  const float* h0 = (const float*)d_in[2];
  const float* c0 = (const float*)d_in[3];
  const float* wihf = (const float*)d_in[4];
  const float* whhf = (const float*)d_in[5];
  const float* bihf = (const float*)d_in[6];
  const float* bhhf = (const float*)d_in[7];
  const float* wihb = (const float*)d_in[8];
  const float* whhb = (const float*)d_in[9];
  const float* bihb = (const float*)d_in[10];
  const float* bhhb = (const float*)d_in[11];
  const float* wout = (const float*)d_in[12];
  const float* bout = (const float*)d_in[13];
  const float* cstart = (const float*)d_in[14];
  const float* cend = (const float*)d_in[15];
  const float* ctrans = (const float*)d_in[16];

  char* ws = (char*)d_ws;
  u16* Abig = (u16*)(ws + OFF_ABIG);
  u16* Bbig = (u16*)(ws + OFF_BBIG);
  float* bias = (float*)(ws + OFF_BIAS);
  float* xg = (float*)(ws + OFF_XG);
  float* hs = (float*)(ws + OFF_HS);
  float* emis = (float*)(ws + OFF_EMIS);
  int* V = (int*)(ws + OFF_V);
  int* flagsA = (int*)(ws + OFF_FLAGS);
  u16* hbufA = (u16*)(ws + OFF_HBUF);
  u16* hbufB = (u16*)(ws + OFF_HBUFB);
  int* flagsB = (int*)(ws + OFF_FLAGSB);
  int* probe = (int*)(ws + OFF_PROBE);
  int* probe2 = (int*)(ws + OFF_PROBE2);
  int* ctrl = (int*)(ws + OFF_CTRL);
  int* out = (int*)d_out;

  hipLaunchKernelGGL(k_prep, dim3(16), dim3(256), 0, stream, amask, V, flagsA, flagsB, probe, probe2, ctrl);
  hipLaunchKernelGGL(k_valid, dim3(32), dim3(256), 0, stream, V, out);
  hipLaunchKernelGGL(k_splitA, dim3(8192), dim3(320), 0, stream, emb, V, Abig);
  hipLaunchKernelGGL(k_splitB, dim3(4096), dim3(320), 0, stream, wihf, wihb, bihf, bhhf, bihb, bhhb, Bbig, bias);
  hipLaunchKernelGGL(k_gemm, dim3(2048), dim3(256), 0, stream, Abig, Bbig, bias, xg, V);
  hipLaunchKernelGGL(k_recur, dim3(256), dim3(256), 0, stream, xg, whhf, whhb, h0, c0, hs, hbufA, hbufB,
                     flagsA, flagsB, probe, probe2, ctrl);
  hipLaunchKernelGGL(k_emis, dim3(2040), dim3(256), 0, stream, hs, wout, bout, emis, V);
  hipLaunchKernelGGL(k_viterbi, dim3(16), dim3(64), 0, stream, emis, V, cstart, cend, ctrans, out);
}

// Round 16
// 1498.650 us; speedup vs baseline: 7.0504x; 1.0219x over previous
//
#include <hip/hip_runtime.h>

typedef unsigned short u16;
typedef unsigned int u32;
typedef __bf16 bf16x8 __attribute__((ext_vector_type(8)));
typedef u16 u16x8 __attribute__((ext_vector_type(8)));
typedef float f32x4 __attribute__((ext_vector_type(4)));
typedef u32 u32x4 __attribute__((ext_vector_type(4)));

#define B_ 16
#define T_ 510
#define H_ 512
#define N_ 4096
#define KSPLIT 2560  // [hi(1280) | lo(1280)]

// workspace offsets (bytes)
#define OFF_ABIG  0ull
#define OFF_BBIG  41943040ull
#define OFF_BIAS  62914560ull
#define OFF_XG    62930944ull
#define OFF_HS    197148672ull
#define OFF_EMIS  230572032ull
#define OFF_V     230735232ull
#define OFF_FLAGS 230735296ull   // flagsA (64 ints)
#define OFF_HBUF  230735552ull   // hbufA (128KB)
// borrowed from the emissions region (written by k_emis only AFTER k_recur):
#define OFF_HBUFB  (OFF_EMIS)              // 128KB
#define OFF_FLAGSB (OFF_EMIS + 131072ull)  // 256B
#define OFF_PROBE  (OFF_EMIS + 131328ull)  // 256B
#define OFF_CTRL   (OFF_EMIS + 131584ull)  // 64B
#define OFF_PROBE2 (OFF_EMIS + 131648ull)  // 256B

#define MAGIC_  0x5EC0FFEE
#define MAGIC2_ 0x7A57C0DE
#define MAGIC3_ 0x3C0DE777
#define POLL_BUDGET 65536
#define PHB_BUDGET  8192
#define ARB_BUDGET  262144

#define GL_LDS(g, s) __builtin_amdgcn_global_load_lds(                      \
    (const __attribute__((address_space(1))) void*)(g),                     \
    (__attribute__((address_space(3))) void*)(s), 16, 0, 0)

__device__ __forceinline__ u16 f2bf(float x) {
  u32 u = __float_as_uint(x);
  u32 r = (u + 0x7fffu + ((u >> 16) & 1u)) >> 16;
  return (u16)r;
}
__device__ __forceinline__ float bf2f(u16 h) { return __uint_as_float(((u32)h) << 16); }

__device__ __forceinline__ int ld_cc(const int* p) {
  int f;
  asm volatile("global_load_dword %0, %1, off sc0 sc1\n\ts_waitcnt vmcnt(0)" : "=v"(f) : "v"(p) : "memory");
  return f;
}
__device__ __forceinline__ int ld_se(const int* p) {
  int f;
  asm volatile("global_load_dword %0, %1, off sc0\n\ts_waitcnt vmcnt(0)" : "=v"(f) : "v"(p) : "memory");
  return f;
}
__device__ __forceinline__ void st_cc(int* p, int v) {
  asm volatile("global_store_dword %0, %1, off sc0 sc1\n\ts_waitcnt vmcnt(0)" :: "v"(p), "v"(v) : "memory");
}
__device__ __forceinline__ void st_plain(int* p, int v) {
  asm volatile("global_store_dword %0, %1, off\n\ts_waitcnt vmcnt(0)" :: "v"(p), "v"(v) : "memory");
}

__device__ __forceinline__ float sigm_f(float x) {  // exact-pass verified (R7/R10/R12)
  float e = __expf(-x);
  return __builtin_amdgcn_rcpf(1.f + e);
}
__device__ __forceinline__ float tanh_f(float x) {
  float e = __expf(2.f * x);
  return 1.f - 2.f * __builtin_amdgcn_rcpf(e + 1.f);
}

// ---------------- K0: lengths + zero all protocol state ----------------
__global__ __launch_bounds__(256) void k_prep(const int* __restrict__ mask, int* __restrict__ V,
                                              int* __restrict__ flagsA, int* __restrict__ flagsB,
                                              int* __restrict__ probe, int* __restrict__ probe2,
                                              int* __restrict__ ctrl) {
  __shared__ int red[4];
  int b = blockIdx.x, tid = threadIdx.x;
  int s = mask[b * 512 + tid] + mask[b * 512 + 256 + tid];
  for (int off = 32; off; off >>= 1) s += __shfl_down(s, off);
  if ((tid & 63) == 0) red[tid >> 6] = s;
  __syncthreads();
  if (tid == 0) V[b] = red[0] + red[1] + red[2] + red[3] - 2;
  if (b == 0 && tid < 64) flagsA[tid] = 0;
  if (b == 2 && tid < 64) flagsB[tid] = 0;
  if (b == 3 && tid < 64) probe[tid] = 0;
  if (b == 4 && tid < 64) probe2[tid] = 0;
  if (b == 1 && tid < 16) ctrl[tid] = 0;
}

// ---------------- valid output ----------------
__global__ __launch_bounds__(256) void k_valid(const int* __restrict__ V, int* __restrict__ out) {
  int idx = blockIdx.x * 256 + threadIdx.x;
  if (idx < B_ * T_) {
    int b = idx / T_, t = idx - b * T_;
    out[B_ * T_ + idx] = (t < V[b]) ? 1 : 0;
  }
}

// ---------------- split x into [hi|lo] bf16, masked ----------------
__global__ __launch_bounds__(320) void k_splitA(const float* __restrict__ emb, const int* __restrict__ V,
                                                u16* __restrict__ Abig) {
  int row = blockIdx.x;
  int k0 = threadIdx.x * 4;
  u16* dst = Abig + (size_t)row * KSPLIT;
  float4 v = {0.f, 0.f, 0.f, 0.f};
  if (row < B_ * T_) {
    int b = row / T_, t = row - b * T_;
    if (t < V[b]) v = *(const float4*)(emb + (size_t)(b * 512 + t + 1) * 1280 + k0);
  }
  float vs[4] = {v.x, v.y, v.z, v.w};
  ushort4 hi, lo;
  u16 h0_ = f2bf(vs[0]); u16 l0_ = f2bf(vs[0] - bf2f(h0_));
  u16 h1_ = f2bf(vs[1]); u16 l1_ = f2bf(vs[1] - bf2f(h1_));
  u16 h2_ = f2bf(vs[2]); u16 l2_ = f2bf(vs[2] - bf2f(h2_));
  u16 h3_ = f2bf(vs[3]); u16 l3_ = f2bf(vs[3] - bf2f(h3_));
  hi.x = h0_; hi.y = h1_; hi.z = h2_; hi.w = h3_;
  lo.x = l0_; lo.y = l1_; lo.z = l2_; lo.w = l3_;
  *(ushort4*)(dst + k0) = hi;
  *(ushort4*)(dst + 1280 + k0) = lo;
}

// ---------------- split W_ih into [hi|lo] bf16 (B^T layout) + bias ----------------
__global__ __launch_bounds__(320) void k_splitB(const float* __restrict__ wf, const float* __restrict__ wb,
                                                const float* __restrict__ bihf, const float* __restrict__ bhhf,
                                                const float* __restrict__ bihb, const float* __restrict__ bhhb,
                                                u16* __restrict__ Bbig, float* __restrict__ bias) {
  int n = blockIdx.x;  // 0..4095
  int k0 = threadIdx.x * 4;
  int d = n >> 11, g = n & 2047;
  const float* w = (d ? wb : wf) + (size_t)g * 1280;
  float4 v = *(const float4*)(w + k0);
  float vs[4] = {v.x, v.y, v.z, v.w};
  ushort4 hi, lo;
  u16 h0_ = f2bf(vs[0]); u16 l0_ = f2bf(vs[0] - bf2f(h0_));
  u16 h1_ = f2bf(vs[1]); u16 l1_ = f2bf(vs[1] - bf2f(h1_));
  u16 h2_ = f2bf(vs[2]); u16 l2_ = f2bf(vs[2] - bf2f(h2_));
  u16 h3_ = f2bf(vs[3]); u16 l3_ = f2bf(vs[3] - bf2f(h3_));
  hi.x = h0_; hi.y = h1_; hi.z = h2_; hi.w = h3_;
  lo.x = l0_; lo.y = l1_; lo.z = l2_; lo.w = l3_;
  u16* dst = Bbig + (size_t)n * KSPLIT;
  *(ushort4*)(dst + k0) = hi;
  *(ushort4*)(dst + 1280 + k0) = lo;
  if (threadIdx.x == 0) bias[n] = d ? (bihb[g] + bhhb[g]) : (bihf[g] + bhhf[g]);
}

// ---------------- Phase A GEMM: C[8192x4096] = Abig * Bbig^T (bf16x3, logical K=3840) ----------------
// Fully-invalid 128-row tiles skip the K-loop and write C = bias (bit-identical).
__global__ __launch_bounds__(256, 2) void k_gemm(const u16* __restrict__ A, const u16* __restrict__ Bt,
                                                 const float* __restrict__ bias, float* __restrict__ C,
                                                 const int* __restrict__ V) {
  __shared__ __align__(16) u16 As[128 * 64];
  __shared__ __align__(16) u16 Bs[128 * 64];
  __shared__ int s_skip;
  const int tid = threadIdx.x;
  const int w = tid >> 6, l = tid & 63;
  const int wm = w >> 1, wn = w & 1;
  const int bid = blockIdx.x;
  const int swz = (bid & 7) * 256 + (bid >> 3);  // XCD-contiguous chunks
  const int bm = swz >> 5, bn = swz & 31;

  {
    const int r = bm * 128 + (tid & 127);
    int invalid;
    if (r >= B_ * T_) {
      invalid = 1;
    } else {
      const int b = r / T_, t = r - b * T_;
      invalid = (t >= V[b]) ? 1 : 0;
    }
    const unsigned long long m = __ballot(invalid);
    if (tid == 0) s_skip = 1;
    __syncthreads();
    if ((l == 0) && (m != ~0ull)) s_skip = 0;
    __syncthreads();
    if (s_skip) {
      const int cc = tid & 127;
      const float bv = bias[bn * 128 + cc];
      const int rh = tid >> 7;
#pragma unroll
      for (int i = 0; i < 64; ++i) {
        const int rr = i * 2 + rh;
        C[(size_t)(bm * 128 + rr) * N_ + bn * 128 + cc] = bv;
      }
      return;
    }
  }

  f32x4 acc[4][4];
#pragma unroll
  for (int m = 0; m < 4; ++m)
#pragma unroll
    for (int n = 0; n < 4; ++n) acc[m][n] = (f32x4){0.f, 0.f, 0.f, 0.f};

  const int rQ = tid >> 3;
  const int cB = (tid & 7) * 16;
  const char* gA = (const char*)(A + (size_t)(bm * 128) * KSPLIT) + cB;
  const char* gB = (const char*)(Bt + (size_t)(bn * 128) * KSPLIT) + cB;

  for (int kt = 0; kt < 60; ++kt) {
    const int s = kt / 20, ks = kt - s * 20;
    const int aOff = ((s == 2) ? 1280 : 0) + ks * 64;
    const int bOff = ((s == 1) ? 1280 : 0) + ks * 64;
    __syncthreads();
#pragma unroll
    for (int q = 0; q < 4; ++q) {
      GL_LDS(gA + ((size_t)(q * 32 + rQ) * KSPLIT + aOff) * 2, (char*)As + q * 4096 + tid * 16);
      GL_LDS(gB + ((size_t)(q * 32 + rQ) * KSPLIT + bOff) * 2, (char*)Bs + q * 4096 + tid * 16);
    }
    __syncthreads();
#pragma unroll
    for (int kc = 0; kc < 2; ++kc) {
      bf16x8 af[4], bfr[4];
      const int kByte = kc * 64 + (l >> 4) * 16;
#pragma unroll
      for (int m = 0; m < 4; ++m)
        af[m] = *(const bf16x8*)((const char*)As + (wm * 64 + m * 16 + (l & 15)) * 128 + kByte);
#pragma unroll
      for (int n = 0; n < 4; ++n)
        bfr[n] = *(const bf16x8*)((const char*)Bs + (wn * 64 + n * 16 + (l & 15)) * 128 + kByte);
#pragma unroll
      for (int m = 0; m < 4; ++m)
#pragma unroll
        for (int n = 0; n < 4; ++n)
          acc[m][n] = __builtin_amdgcn_mfma_f32_16x16x32_bf16(af[m], bfr[n], acc[m][n], 0, 0, 0);
    }
  }
#pragma unroll
  for (int n = 0; n < 4; ++n) {
    const int gc = bn * 128 + wn * 64 + n * 16 + (l & 15);
    const float bv = bias[gc];
#pragma unroll
    for (int m = 0; m < 4; ++m) {
      const int gr0 = bm * 128 + wm * 64 + m * 16 + (l >> 4) * 4;
#pragma unroll
      for (int r = 0; r < 4; ++r) C[(size_t)(gr0 + r) * N_ + gc] = acc[m][n][r] + bv;
    }
  }
}

// ---------------- recurrence body (R12 protocol + R7 direct gate mapping; no hsh bounce) ----------------
// COH=2 FAST: plain stores (L2-dirty) + sc0 loads; poll has sc0sc1 liveness escape each 256 iters.
// COH=1 MID : plain stores + sc0sc1 loads. COH=0: cross-XCD fallback.
// Epilogue: acc -> epil (wave-private write) -> __syncthreads -> gate-thread (sb=tid>>4,
// su=tid&15) reads its 4 gates cross-wave from epil (slab stride 328), gate math, coalesced
// emit. R10 lesson: xg prefetch at TOP of loop. R11/R13 lesson: 256-thread blocks only.
template <int COH>
__device__ void run_recur(int dir, int sub, const float* __restrict__ xg, const float* __restrict__ whh,
                          const float* __restrict__ h0, const float* __restrict__ c0,
                          float* __restrict__ hs, u16* __restrict__ hbuf, int* __restrict__ flags,
                          u16* lds_a, float* epil) {
  const int tid = threadIdx.x;
  const int w = tid >> 6, l = tid & 63;
  const int c = l & 15, kg = l >> 4;
  const int gate = c >> 2, uloc = c & 3;
  const int ug = sub * 16 + w * 4 + uloc;
  constexpr int GB = (COH != 0) ? 9 : 0;

  __syncthreads();  // safe re-entry

  // preload W_hh fragments, split bf16 hi/lo (held in VGPRs)
  bf16x8 whi[16], wlo[16];
  {
    const float* wrow = whh + (size_t)(gate * 512 + ug) * 512 + kg * 8;
#pragma unroll
    for (int kc = 0; kc < 16; ++kc) {
      float4 v0 = *(const float4*)(wrow + kc * 32);
      float4 v1 = *(const float4*)(wrow + kc * 32 + 4);
      float vs[8] = {v0.x, v0.y, v0.z, v0.w, v1.x, v1.y, v1.z, v1.w};
      u16x8 hi, lo;
#pragma unroll
      for (int j = 0; j < 8; ++j) {
        u16 h = f2bf(vs[j]);
        hi[j] = h;
        lo[j] = f2bf(vs[j] - bf2f(h));
      }
      whi[kc] = __builtin_bit_cast(bf16x8, hi);
      wlo[kc] = __builtin_bit_cast(bf16x8, lo);
    }
  }

  // gate-math thread owns (sample sb, block-unit su) for creg/emit/hs (R7-verified mapping)
  const int sb = tid >> 4, su = tid & 15;
  const int gu = sub * 16 + su;
  const int ew = su >> 2, ec = su & 3;
  float creg = c0[(dir * 16 + sb) * 512 + gu];
  {  // publish initial h (split) into parity-0 buffer (one-time, coalesced)
    float h = h0[(dir * 16 + sb) * 512 + gu];
    u16 hh = f2bf(h), hl = f2bf(h - bf2f(hh));
    size_t base = (size_t)(dir * 2) * 8192;
    u16* p0 = hbuf + base + sb * 512 + gu;
    if constexpr (COH != 0) {
      asm volatile("global_store_short %0, %1, off\n\tglobal_store_short %2, %3, off\n\ts_waitcnt vmcnt(0)"
                   :: "v"(p0), "v"((u32)hh), "v"(p0 + 8192), "v"((u32)hl) : "memory");
    } else {
      asm volatile("global_store_short %0, %1, off sc0 sc1\n\tglobal_store_short %2, %3, off sc0 sc1\n\ts_waitcnt vmcnt(0)"
                   :: "v"(p0), "v"((u32)hh), "v"(p0 + 8192), "v"((u32)hl) : "memory");
    }
  }
  __syncthreads();
  if (tid == 0) {
    if constexpr (COH != 0) st_plain(flags + dir * 32 + sub, 1 + GB);
    else st_cc(flags + dir * 32 + sub, 1 + GB);
  }

  for (int t = 0; t < T_; ++t) {
    const int trow = dir ? (T_ - 1 - t) : t;
    // xg prefetch into MFMA accumulator init (top of loop = after previous release)
    f32x4 acc0;
    {
      const int n = dir * 2048 + gate * 512 + ug;
#pragma unroll
      for (int r = 0; r < 4; ++r) acc0[r] = xg[(size_t)((kg * 4 + r) * T_ + trow) * N_ + n];
    }
    // per-dir barrier: one vectorized 32-flag poll
    if (w == 0) {
      const int* fp = flags + (dir << 5) + (l & 31);
      int it = 0;
      while (true) {
        int f;
        if constexpr (COH == 2) {
          ++it;
          if ((it & 255) == 0)
            asm volatile("global_load_dword %0, %1, off sc0 sc1\n\ts_waitcnt vmcnt(0)" : "=v"(f) : "v"(fp) : "memory");
          else
            asm volatile("global_load_dword %0, %1, off sc0\n\ts_waitcnt vmcnt(0)" : "=v"(f) : "v"(fp) : "memory");
        } else {
          asm volatile("global_load_dword %0, %1, off sc0 sc1\n\ts_waitcnt vmcnt(0)" : "=v"(f) : "v"(fp) : "memory");
        }
        if (__all(f >= t + 1 + GB)) break;
        if constexpr (COH == 0) __builtin_amdgcn_s_sleep(1);
      }
    }
    __syncthreads();

    // stage h(t) 32KB into LDS (FAST: L2-served sc0; else sc0sc1)
    {
      const u16* src = hbuf + (size_t)(((t & 1) * 2 + dir) * 2) * 8192;
      u32x4 v[8];
#pragma unroll
      for (int q = 0; q < 8; ++q) {
        const char* p = (const char*)src + q * 4096 + tid * 16;
        if constexpr (COH == 2)
          asm volatile("global_load_dwordx4 %0, %1, off sc0" : "=v"(v[q]) : "v"(p) : "memory");
        else
          asm volatile("global_load_dwordx4 %0, %1, off sc0 sc1" : "=v"(v[q]) : "v"(p) : "memory");
      }
      asm volatile("s_waitcnt vmcnt(0)" ::: "memory");
      __builtin_amdgcn_sched_barrier(0);
#pragma unroll
      for (int q = 0; q < 8; ++q) {
        int off = q * 4096 + tid * 16;
        int var = off >> 14;
        int rem = off & 16383;
        int b = rem >> 10;
        int inrow = rem & 1023;
        *(u32x4*)((char*)lds_a + var * 16384 + b * 1024 + (inrow ^ ((b & 7) << 4))) = v[q];
      }
    }
    __syncthreads();

    // 6 independent accumulator chains (acc0 carries xg)
    f32x4 acc1 = (f32x4){0.f, 0.f, 0.f, 0.f};
    f32x4 acc2 = (f32x4){0.f, 0.f, 0.f, 0.f};
    f32x4 acc3 = (f32x4){0.f, 0.f, 0.f, 0.f};
    f32x4 acc4 = (f32x4){0.f, 0.f, 0.f, 0.f};
    f32x4 acc5 = (f32x4){0.f, 0.f, 0.f, 0.f};
#pragma unroll
    for (int kc = 0; kc < 16; ++kc) {
      const int rowb = l & 15;
      const int koff = (kc * 64 + kg * 16) ^ ((rowb & 7) << 4);
      bf16x8 ahi = *(const bf16x8*)((const char*)lds_a + rowb * 1024 + koff);
      bf16x8 alo = *(const bf16x8*)((const char*)lds_a + 16384 + rowb * 1024 + koff);
      if (kc & 1) {
        acc3 = __builtin_amdgcn_mfma_f32_16x16x32_bf16(ahi, whi[kc], acc3, 0, 0, 0);
        acc4 = __builtin_amdgcn_mfma_f32_16x16x32_bf16(ahi, wlo[kc], acc4, 0, 0, 0);
        acc5 = __builtin_amdgcn_mfma_f32_16x16x32_bf16(alo, whi[kc], acc5, 0, 0, 0);
      } else {
        acc0 = __builtin_amdgcn_mfma_f32_16x16x32_bf16(ahi, whi[kc], acc0, 0, 0, 0);
        acc1 = __builtin_amdgcn_mfma_f32_16x16x32_bf16(ahi, wlo[kc], acc1, 0, 0, 0);
        acc2 = __builtin_amdgcn_mfma_f32_16x16x32_bf16(alo, whi[kc], acc2, 0, 0, 0);
      }
    }
    f32x4 acc = ((acc0 + acc3) + (acc1 + acc4)) + (acc2 + acc5);

    // epilogue: acc -> epil (wave slab stride 328, row stride 20); cross-wave gate read
#pragma unroll
    for (int r = 0; r < 4; ++r) epil[w * 328 + (kg * 4 + r) * 20 + c] = acc[r];
    __syncthreads();
    const float gi = epil[ew * 328 + sb * 20 + 0 + ec];
    const float gf = epil[ew * 328 + sb * 20 + 4 + ec];
    const float gg = epil[ew * 328 + sb * 20 + 8 + ec];
    const float go = epil[ew * 328 + sb * 20 + 12 + ec];
    const float si = sigm_f(gi);
    const float sf = sigm_f(gf);
    const float so = sigm_f(go);
    const float tg = tanh_f(gg);
    creg = sf * creg + si * tg;
    const float h = so * tanh_f(creg);
    // emit: thread owns (sb,su) -> coalesced stores, no redistribution
    {
      u16 hh = f2bf(h), hl = f2bf(h - bf2f(hh));
      size_t base = (size_t)((((t + 1) & 1) * 2 + dir) * 2) * 8192;
      u16* p0 = hbuf + base + sb * 512 + gu;
      if constexpr (COH != 0) {
        asm volatile("global_store_short %0, %1, off\n\tglobal_store_short %2, %3, off\n\ts_waitcnt vmcnt(0)"
                     :: "v"(p0), "v"((u32)hh), "v"(p0 + 8192), "v"((u32)hl) : "memory");
      } else {
        asm volatile("global_store_short %0, %1, off sc0 sc1\n\tglobal_store_short %2, %3, off sc0 sc1\n\ts_waitcnt vmcnt(0)"
                     :: "v"(p0), "v"((u32)hh), "v"(p0 + 8192), "v"((u32)hl) : "memory");
      }
    }
    __syncthreads();  // all emits drained
    if (tid == 0) {  // clean release: nothing outstanding in this wave
      if constexpr (COH != 0) st_plain(flags + dir * 32 + sub, t + 2 + GB);
      else st_cc(flags + dir * 32 + sub, t + 2 + GB);
    }
    hs[(size_t)((dir * 16 + sb) * T_ + trow) * 512 + gu] = h;  // off critical path
  }
}

// ---------------- persistent BiLSTM recurrence: probe-gated XCD teams + sc0 capability probe ----------------
__global__ __launch_bounds__(256, 1) void k_recur(const float* __restrict__ xg, const float* __restrict__ whh_f,
                                                  const float* __restrict__ whh_b, const float* __restrict__ h0,
                                                  const float* __restrict__ c0, float* __restrict__ hs,
                                                  u16* __restrict__ hbufA, u16* __restrict__ hbufB,
                                                  int* __restrict__ flagsA, int* __restrict__ flagsB,
                                                  int* __restrict__ probe, int* __restrict__ probe2,
                                                  int* __restrict__ ctrl) {
  __shared__ __align__(16) u16 lds_a[16384];
  __shared__ float epil[4 * 328];
  __shared__ int s_act, s_cfg;

  const int tid = threadIdx.x;

  if (tid == 0) {
    int xcc;
    asm volatile("s_getreg_b32 %0, hwreg(HW_REG_XCC_ID)" : "=s"(xcc));
    xcc &= 7;
    int slot = 99;
    if (xcc < 2) slot = __hip_atomic_fetch_add(&ctrl[4 + xcc], 1, __ATOMIC_RELAXED, __HIP_MEMORY_SCOPE_AGENT);
    const int roleA = (xcc < 2 && slot < 32);
    const int dir = xcc, sub = slot;
    // flag milestones: 2 arrived / 3 A-ok / 4 r1-ok / 5 r2-armed / 6 FAST-ok / 7,8 fail. All < 10.
    if (roleA) {
      int* myflag = flagsA + dir * 32 + sub;
      const int fb = dir * 32;
      int mg = MAGIC_;
      asm volatile("global_store_dword %0, %1, off\n\ts_waitcnt vmcnt(0)" :: "v"(probe + fb + sub), "v"(mg) : "memory");
      st_cc(myflag, 2);
      bool complete = false;
      for (int it = 0; it < POLL_BUDGET && !complete; ++it) {
        complete = true;
        for (int j = 0; j < 32; ++j)
          if (ld_cc(flagsA + fb + j) < 2) { complete = false; break; }
        if (!complete) __builtin_amdgcn_s_sleep(16);
      }
      bool Aok = complete;
      if (Aok)
        for (int j = 0; j < 32; ++j)
          if (ld_cc(probe + fb + j) != MAGIC_) { Aok = false; break; }
      if (Aok) {
        int m2 = MAGIC2_;
        asm volatile("global_store_dword %0, %1, off\n\ts_waitcnt vmcnt(0)" :: "v"(probe2 + fb + sub), "v"(m2) : "memory");
      }
      st_cc(myflag, Aok ? 3 : 7);
      bool any7 = !Aok, arrived = false;
      for (int it = 0; it < PHB_BUDGET && !arrived && !any7; ++it) {
        arrived = true;
        for (int j = 0; j < 32; ++j) {
          int f = ld_cc(flagsA + fb + j);
          if (f == 7) { any7 = true; break; }
          if (f < 3) { arrived = false; break; }
        }
        if (!arrived && !any7) __builtin_amdgcn_s_sleep(4);
      }
      if (Aok && arrived && !any7) {
        bool r1 = true;
        for (int j = 0; j < 32; ++j)
          if (ld_se(probe2 + fb + j) != MAGIC2_) { r1 = false; break; }
        st_cc(myflag, r1 ? 4 : 8);
        if (r1) {
          bool all4 = false, any8 = false;
          for (int it = 0; it < PHB_BUDGET && !all4 && !any8; ++it) {
            all4 = true;
            for (int j = 0; j < 32; ++j) {
              int f = ld_cc(flagsA + fb + j);
              if (f == 8) { any8 = true; break; }
              if (f < 4) { all4 = false; break; }
            }
            if (!all4 && !any8) __builtin_amdgcn_s_sleep(4);
          }
          if (all4 && !any8) {
            int m3 = MAGIC3_;
            asm volatile("global_store_dword %0, %1, off\n\ts_waitcnt vmcnt(0)" :: "v"(probe2 + fb + sub), "v"(m3) : "memory");
            st_cc(myflag, 5);
            bool all5 = false;
            for (int it = 0; it < PHB_BUDGET && !all5; ++it) {
              all5 = true;
              for (int j = 0; j < 32; ++j)
                if (ld_cc(flagsA + fb + j) < 5) { all5 = false; break; }
              if (!all5) __builtin_amdgcn_s_sleep(4);
            }
            bool r2 = all5;
            if (r2)
              for (int j = 0; j < 32; ++j)
                if (ld_se(probe2 + fb + j) != MAGIC3_) { r2 = false; break; }
            st_cc(myflag, r2 ? 6 : 8);
          }
        }
      }
      if (sub == 0) {
        int verdict = Aok ? 1 : 2;
        for (int it = 0; it < PHB_BUDGET; ++it) {
          int n6 = 0;
          bool bad7 = false, bad8 = false, pending = false;
          for (int j = 0; j < 32; ++j) {
            int f = ld_cc(flagsA + fb + j);
            if (f == 7) { bad7 = true; break; }
            if (f == 8) { bad8 = true; break; }
            if (f == 6) ++n6;
            else pending = true;
          }
          if (bad7) { verdict = 2; break; }
          if (bad8) { verdict = Aok ? 1 : 2; break; }
          if (n6 == 32) { verdict = 3; break; }
          if (pending) __builtin_amdgcn_s_sleep(4);
        }
        st_cc(&ctrl[12 + dir], verdict);
      }
    }

    if (blockIdx.x == 0) {  // arbiter
      int v0 = 0, v1 = 0;
      for (int it = 0; it < ARB_BUDGET; ++it) {
        v0 = ld_cc(&ctrl[12]);
        v1 = ld_cc(&ctrl[13]);
        if (v0 && v1) break;
        __builtin_amdgcn_s_sleep(16);
      }
      if (!v0) v0 = 2;
      if (!v1) v1 = 2;
      st_cc(&ctrl[14], 0x100 | v0 | (v1 << 4));
    }

    int cfg;
    do {
      cfg = ld_cc(&ctrl[14]);
      if (!cfg) __builtin_amdgcn_s_sleep(16);
    } while (!cfg);

    s_cfg = cfg;
    int md = (cfg >> (dir * 4)) & 15;
    s_act = (roleA && md != 2) ? (dir | (sub << 1) | (md << 6)) : -1;
  }
  __syncthreads();
  const int act = s_act, cfg = s_cfg;

  if (act >= 0) {
    const int adir = act & 1, asub = (act >> 1) & 31, md = act >> 6;
    if (md == 3)
      run_recur<2>(adir, asub, xg, adir ? whh_b : whh_f, h0, c0, hs, hbufA, flagsA, lds_a, epil);
    else
      run_recur<1>(adir, asub, xg, adir ? whh_b : whh_f, h0, c0, hs, hbufA, flagsA, lds_a, epil);
  }
  if (blockIdx.x < 64) {  // fallback duty for any dir in FALLBACK mode
    const int mdir = (int)blockIdx.x >> 5, msub = (int)blockIdx.x & 31;
    if (((cfg >> (mdir * 4)) & 15) == 2)
      run_recur<0>(mdir, msub, xg, mdir ? whh_b : whh_f, h0, c0, hs, hbufB, flagsB, lds_a, epil);
  }
}

// ---------------- emissions: e = [hf|hb] @ w_out + b_out (valid rows only) ----------------
__global__ __launch_bounds__(256) void k_emis(const float* __restrict__ hs, const float* __restrict__ wout,
                                              const float* __restrict__ bout, float* __restrict__ e,
                                              const int* __restrict__ V) {
  const int tid = threadIdx.x;
  const int w = tid >> 6, l = tid & 63;
  const int row = blockIdx.x * 4 + w;  // < 8160
  const int b = row / T_, t = row - b * T_;
  if (t >= V[b]) return;
  const float* hf = hs + (size_t)(b * T_ + t) * 512;
  const float* hb = hs + (size_t)((16 + b) * T_ + t) * 512;
  float a0 = 0, a1 = 0, a2 = 0, a3 = 0, a4 = 0;
#pragma unroll
  for (int it = 0; it < 8; ++it) {
    int u = it * 64 + l;
    float hv = hf[u];
    const float* wr = wout + u * 5;
    a0 += hv * wr[0]; a1 += hv * wr[1]; a2 += hv * wr[2]; a3 += hv * wr[3]; a4 += hv * wr[4];
  }
#pragma unroll
  for (int it = 0; it < 8; ++it) {
    int u = it * 64 + l;
    float hv = hb[u];
    const float* wr = wout + (512 + u) * 5;
    a0 += hv * wr[0]; a1 += hv * wr[1]; a2 += hv * wr[2]; a3 += hv * wr[3]; a4 += hv * wr[4];
  }
  for (int off = 32; off; off >>= 1) {
    a0 += __shfl_down(a0, off);
    a1 += __shfl_down(a1, off);
    a2 += __shfl_down(a2, off);
    a3 += __shfl_down(a3, off);
    a4 += __shfl_down(a4, off);
  }
  if (l == 0) {
    float* ep = e + (size_t)row * 5;
    ep[0] = a0 + bout[0];
    ep[1] = a1 + bout[1];
    ep[2] = a2 + bout[2];
    ep[3] = a3 + bout[3];
    ep[4] = a4 + bout[4];
  }
}

// ---------------- Viterbi per batch ----------------
__global__ __launch_bounds__(64) void k_viterbi(const float* __restrict__ e, const int* __restrict__ V,
                                                const float* __restrict__ start, const float* __restrict__ endv,
                                                const float* __restrict__ trans, int* __restrict__ out) {
  __shared__ float els[T_ * 5];
  __shared__ unsigned char hist[(T_ - 1) * 5];
  __shared__ float strans[25];
  const int b = blockIdx.x, l = threadIdx.x;
  for (int i = l; i < T_ * 5; i += 64) els[i] = e[(size_t)b * T_ * 5 + i];
  if (l < 25) strans[l] = trans[l];
  const int Vb = V[b];
  __syncthreads();
  const int cl = (l < 5) ? l : 0;
  float score = (l < 5) ? (start[l] + els[l]) : -1e30f;
  for (int t = 1; t < T_; ++t) {
    const bool valid = t < Vb;
    float m = -1e30f;
    int arg = 0;
#pragma unroll
    for (int p = 0; p < 5; ++p) {
      float v = __shfl(score, p) + strans[p * 5 + cl];
      if (v > m) { m = v; arg = p; }
    }
    if (l < 5) {
      if (valid) {
        score = m + els[t * 5 + l];
        hist[(t - 1) * 5 + l] = (unsigned char)arg;
      } else {
        hist[(t - 1) * 5 + l] = (unsigned char)l;
      }
    }
  }
  float sc = (l < 5) ? (score + endv[l]) : -1e30f;
  int last = 0;
  float mb = -1e30f;
#pragma unroll
  for (int p = 0; p < 5; ++p) {
    float v = __shfl(sc, p);
    if (v > mb) { mb = v; last = p; }
  }
  __syncthreads();
  if (l == 0) {
    int tag = last;
    out[b * T_ + (T_ - 1)] = tag;
    for (int t = T_ - 2; t >= 0; --t) {
      tag = hist[t * 5 + tag];
      out[b * T_ + t] = tag;
    }
  }
}

extern "C" void kernel_launch(void* const* d_in, const int* in_sizes, int n_in, void* d_out, int out_size,
                              void* d_ws, size_t ws_size, hipStream_t stream) {
  const float* emb = (const float*)d_in[0];
  const int* amask = (const int*)d_in[1];
  const float* h0 = (const float*)d_in[2];
  const float* c0 = (const float*)d_in[3];
  const float* wihf = (const float*)d_in[4];
  const float* whhf = (const float*)d_in[5];
  const float* bihf = (const float*)d_in[6];
  const float* bhhf = (const float*)d_in[7];
  const float* wihb = (const float*)d_in[8];
  const float* whhb = (const float*)d_in[9];
  const float* bihb = (const float*)d_in[10];
  const float* bhhb = (const float*)d_in[11];
  const float* wout = (const float*)d_in[12];
  const float* bout = (const float*)d_in[13];
  const float* cstart = (const float*)d_in[14];
  const float* cend = (const float*)d_in[15];
  const float* ctrans = (const float*)d_in[16];

  char* ws = (char*)d_ws;
  u16* Abig = (u16*)(ws + OFF_ABIG);
  u16* Bbig = (u16*)(ws + OFF_BBIG);
  float* bias = (float*)(ws + OFF_BIAS);
  float* xg = (float*)(ws + OFF_XG);
  float* hs = (float*)(ws + OFF_HS);
  float* emis = (float*)(ws + OFF_EMIS);
  int* V = (int*)(ws + OFF_V);
  int* flagsA = (int*)(ws + OFF_FLAGS);
  u16* hbufA = (u16*)(ws + OFF_HBUF);
  u16* hbufB = (u16*)(ws + OFF_HBUFB);
  int* flagsB = (int*)(ws + OFF_FLAGSB);
  int* probe = (int*)(ws + OFF_PROBE);
  int* probe2 = (int*)(ws + OFF_PROBE2);
  int* ctrl = (int*)(ws + OFF_CTRL);
  int* out = (int*)d_out;

  hipLaunchKernelGGL(k_prep, dim3(16), dim3(256), 0, stream, amask, V, flagsA, flagsB, probe, probe2, ctrl);
  hipLaunchKernelGGL(k_valid, dim3(32), dim3(256), 0, stream, V, out);
  hipLaunchKernelGGL(k_splitA, dim3(8192), dim3(320), 0, stream, emb, V, Abig);
  hipLaunchKernelGGL(k_splitB, dim3(4096), dim3(320), 0, stream, wihf, wihb, bihf, bhhf, bihb, bhhb, Bbig, bias);
  hipLaunchKernelGGL(k_gemm, dim3(2048), dim3(256), 0, stream, Abig, Bbig, bias, xg, V);
  hipLaunchKernelGGL(k_recur, dim3(256), dim3(256), 0, stream, xg, whhf, whhb, h0, c0, hs, hbufA, hbufB,
                     flagsA, flagsB, probe, probe2, ctrl);
  hipLaunchKernelGGL(k_emis, dim3(2040), dim3(256), 0, stream, hs, wout, bout, emis, V);
  hipLaunchKernelGGL(k_viterbi, dim3(16), dim3(64), 0, stream, emis, V, cstart, cend, ctrans, out);
}